// Round 6
// baseline (360.424 us; speedup 1.0000x reference)
//
#include <hip/hip_runtime.h>
#include <math.h>

#define B_ 16
#define M_ 1024
#define N_ 1024
#define D_ 512
#define MP1 1025
#define NP1 1025
#define NUM_SINK 8
#define BK 64
#define SH_STRIDE 1032   // fp16 row stride (elements), 16B-aligned rows
#define VSTR 1028        // v stride (floats), 16B-aligned
#define NCH 129          // chunks of 8 rows (128*8=1024 rows + 1 chunk for row 1024)
// log(1/2048), log(1/2)
#define LOG_NORM (-7.6246189861593985f)
#define LOG_HALF (-0.6931471805599453f)

typedef __attribute__((ext_vector_type(8))) short bf16x8;
typedef __attribute__((ext_vector_type(4))) float f32x4;
typedef __attribute__((ext_vector_type(8))) _Float16 h16x8;

__device__ inline short f2bf(float x) {
    unsigned u = __builtin_bit_cast(unsigned, x);
    u = (u + 0x7FFFu + ((u >> 16) & 1u)) >> 16;
    return (short)u;
}

__device__ inline void gload16(const void* g, void* l) {
    __builtin_amdgcn_global_load_lds(
        (const __attribute__((address_space(1))) unsigned int*)g,
        (__attribute__((address_space(3))) unsigned int*)l, 16, 0, 0);
}

// ---------------- norms + optional bf16 conversion: one wave per feature row ----------------
template<bool CONV>
__global__ __launch_bounds__(256) void norms_kernel_t(
    const float* __restrict__ tf, const float* __restrict__ df,
    float* __restrict__ inv1, float* __restrict__ inv2,
    unsigned short* __restrict__ tfh, unsigned short* __restrict__ dfh)
{
    int w = (blockIdx.x * 256 + threadIdx.x) >> 6;
    int lane = threadIdx.x & 63;
    if (w >= B_ * 2048) return;
    int b = w >> 11;
    int rr = w & 2047;
    const float* src;
    float* dst;
    unsigned short* dsth;
    if (rr < M_) { src = tf + ((size_t)b * M_ + rr) * D_;        dst = inv1 + b * M_ + rr;
                   dsth = CONV ? tfh + ((size_t)b * M_ + rr) * D_ : nullptr; }
    else         { src = df + ((size_t)b * N_ + (rr - M_)) * D_; dst = inv2 + b * N_ + (rr - M_);
                   dsth = CONV ? dfh + ((size_t)b * N_ + (rr - M_)) * D_ : nullptr; }
    float4 x = *(const float4*)(src + lane * 4);
    float4 y = *(const float4*)(src + 256 + lane * 4);
    if (CONV) {
        ushort4 hx, hy;
        hx.x = (unsigned short)f2bf(x.x); hx.y = (unsigned short)f2bf(x.y);
        hx.z = (unsigned short)f2bf(x.z); hx.w = (unsigned short)f2bf(x.w);
        hy.x = (unsigned short)f2bf(y.x); hy.y = (unsigned short)f2bf(y.y);
        hy.z = (unsigned short)f2bf(y.z); hy.w = (unsigned short)f2bf(y.w);
        *(ushort4*)(dsth + lane * 4) = hx;
        *(ushort4*)(dsth + 256 + lane * 4) = hy;
    }
    float ss = x.x*x.x + x.y*x.y + x.z*x.z + x.w*x.w
             + y.x*y.x + y.y*y.y + y.z*y.z + y.w*y.w;
    #pragma unroll
    for (int o = 32; o; o >>= 1) ss += __shfl_xor(ss, o);
    if (lane == 0) *dst = 1.0f / sqrtf(ss);
}

// ---------------- MFMA GEMM + epilogue: S = (cos*mask - 1)/lambda ----------------
// MODE 0: fp32 out, f2bf reg-staging.  MODE 1: fp16 out, f2bf reg-staging.
// MODE 2: fp16 out, global_load_lds from pre-converted bf16 (swizzled source).
template<int MODE>
__global__ __launch_bounds__(256) void gemm_s_kernel(
    const void* __restrict__ A, const void* __restrict__ Bm,
    const float* __restrict__ tl, const float* __restrict__ dl,
    const float* __restrict__ inv1, const float* __restrict__ inv2,
    const float* __restrict__ eps_p, void* __restrict__ Sout)
{
    __shared__ __align__(16) unsigned short As[128 * BK];
    __shared__ __align__(16) unsigned short Bs[128 * BK];

    int flat = blockIdx.x;
    int swz = (flat & 7) * 128 + (flat >> 3);
    int jb = swz & 7, ib = (swz >> 3) & 7;
    int b  = swz >> 6;
    int i0 = ib * 128;
    int j0 = jb * 128;

    int tid  = threadIdx.x;
    int lane = tid & 63;
    int w    = tid >> 6;
    int wm   = w >> 1, wn = w & 1;

    f32x4 acc[4][4] = {};

    if constexpr (MODE == 2) {
        const unsigned short* Ah = (const unsigned short*)A  + (size_t)b * M_ * D_;
        const unsigned short* Bh = (const unsigned short*)Bm + (size_t)b * N_ * D_;
        int gcol = ((lane & 7) ^ (lane >> 3)) << 3;   // pre-swizzled source element offset
        int rloc = lane >> 3;
        for (int k0 = 0; k0 < D_; k0 += BK) {
            #pragma unroll
            for (int c = 0; c < 4; ++c) {
                int r = (w * 4 + c) * 8 + rloc;
                gload16(Ah + (size_t)(i0 + r) * D_ + k0 + gcol,
                        (char*)As + (w * 4 + c) * 1024 + lane * 16);
                gload16(Bh + (size_t)(j0 + r) * D_ + k0 + gcol,
                        (char*)Bs + (w * 4 + c) * 1024 + lane * 16);
            }
            __syncthreads();
            #pragma unroll
            for (int ks = 0; ks < 2; ++ks) {
                int kb = ks * 64 + ((lane >> 4) << 4);
                bf16x8 af[4], bfr[4];
                #pragma unroll
                for (int m = 0; m < 4; ++m) {
                    int ra = wm * 64 + m * 16 + (lane & 15);
                    af[m] = *(const bf16x8*)((const char*)As + ra * 128 + (kb ^ ((ra & 7) << 4)));
                    int rb = wn * 64 + m * 16 + (lane & 15);
                    bfr[m] = *(const bf16x8*)((const char*)Bs + rb * 128 + (kb ^ ((rb & 7) << 4)));
                }
                #pragma unroll
                for (int m = 0; m < 4; ++m)
                    #pragma unroll
                    for (int n = 0; n < 4; ++n)
                        acc[m][n] = __builtin_amdgcn_mfma_f32_16x16x32_bf16(af[m], bfr[n], acc[m][n], 0, 0, 0);
            }
            __syncthreads();
        }
    } else {
        const float* Ab = (const float*)A  + (size_t)b * M_ * D_;
        const float* Bb = (const float*)Bm + (size_t)b * N_ * D_;
        int seg   = tid & 7;
        int rbase = tid >> 3;
        for (int k0 = 0; k0 < D_; k0 += BK) {
            #pragma unroll
            for (int rr = 0; rr < 4; ++rr) {
                int r = rbase + rr * 32;
                int colx = (seg * 16) ^ ((r & 7) << 4);
                {
                    const float* pa = Ab + (size_t)(i0 + r) * D_ + k0 + seg * 8;
                    float4 a0 = *(const float4*)pa;
                    float4 a1 = *(const float4*)(pa + 4);
                    bf16x8 hv;
                    hv[0] = f2bf(a0.x); hv[1] = f2bf(a0.y); hv[2] = f2bf(a0.z); hv[3] = f2bf(a0.w);
                    hv[4] = f2bf(a1.x); hv[5] = f2bf(a1.y); hv[6] = f2bf(a1.z); hv[7] = f2bf(a1.w);
                    *(bf16x8*)((char*)As + r * 128 + colx) = hv;
                }
                {
                    const float* pb = Bb + (size_t)(j0 + r) * D_ + k0 + seg * 8;
                    float4 b0 = *(const float4*)pb;
                    float4 b1 = *(const float4*)(pb + 4);
                    bf16x8 hv;
                    hv[0] = f2bf(b0.x); hv[1] = f2bf(b0.y); hv[2] = f2bf(b0.z); hv[3] = f2bf(b0.w);
                    hv[4] = f2bf(b1.x); hv[5] = f2bf(b1.y); hv[6] = f2bf(b1.z); hv[7] = f2bf(b1.w);
                    *(bf16x8*)((char*)Bs + r * 128 + colx) = hv;
                }
            }
            __syncthreads();
            #pragma unroll
            for (int ks = 0; ks < 2; ++ks) {
                int kb = ks * 64 + ((lane >> 4) << 4);
                bf16x8 af[4], bfr[4];
                #pragma unroll
                for (int m = 0; m < 4; ++m) {
                    int ra = wm * 64 + m * 16 + (lane & 15);
                    af[m] = *(const bf16x8*)((const char*)As + ra * 128 + (kb ^ ((ra & 7) << 4)));
                    int rb = wn * 64 + m * 16 + (lane & 15);
                    bfr[m] = *(const bf16x8*)((const char*)Bs + rb * 128 + (kb ^ ((rb & 7) << 4)));
                }
                #pragma unroll
                for (int m = 0; m < 4; ++m)
                    #pragma unroll
                    for (int n = 0; n < 4; ++n)
                        acc[m][n] = __builtin_amdgcn_mfma_f32_16x16x32_bf16(af[m], bfr[n], acc[m][n], 0, 0, 0);
            }
            __syncthreads();
        }
    }

    float lam = expf(eps_p[0]) + 0.03f;
    float inv_lam = 1.0f / lam;
    int crow0 = i0 + wm * 64;
    int ccol0 = j0 + wn * 64;
    int rlane = lane >> 4;
    int clane = lane & 15;

    float invb_[4], dlx_[4], dly_[4];
    #pragma unroll
    for (int n = 0; n < 4; ++n) {
        int j = ccol0 + n * 16 + clane;
        invb_[n] = inv2[b * N_ + j];
        dlx_[n]  = dl[((size_t)b * N_ + j) * 2 + 0];
        dly_[n]  = dl[((size_t)b * N_ + j) * 2 + 1];
    }
    #pragma unroll
    for (int m = 0; m < 4; ++m) {
        #pragma unroll
        for (int reg = 0; reg < 4; ++reg) {
            int i = crow0 + m * 16 + rlane * 4 + reg;
            float inva = inv1[b * M_ + i];
            float tlx  = tl[((size_t)b * M_ + i) * 2 + 0];
            float tly  = tl[((size_t)b * M_ + i) * 2 + 1];
            #pragma unroll
            for (int n = 0; n < 4; ++n) {
                float cosv = acc[m][n][reg] * inva * invb_[n];
                float dx = tlx - dlx_[n];
                float dy = tly - dly_[n];
                float msk = (sqrtf(dx * dx + dy * dy) <= 0.3f) ? 1.0f : 0.0f;
                float val = (cosv * msk - 1.0f) * inv_lam;
                int col = ccol0 + n * 16 + clane;
                if (MODE >= 1) {
                    _Float16* Srow = (_Float16*)Sout + ((size_t)b * MP1 + i) * SH_STRIDE;
                    Srow[col] = (_Float16)val;
                } else {
                    float* Srow = (float*)Sout + ((size_t)b * MP1 + i) * NP1;
                    Srow[col] = val;
                }
            }
        }
    }
}

// ---------------- init: zero v + fill fp16 dustbin row/col ----------------
__global__ __launch_bounds__(256) void init_h_kernel(
    float* __restrict__ v, _Float16* __restrict__ Sh,
    const float* __restrict__ alpha_p, const float* __restrict__ eps_p)
{
    int t = blockIdx.x * 256 + threadIdx.x;
    if (t < B_ * VSTR) v[t] = 0.f;
    int u = t - B_ * VSTR;
    if (u >= 0 && u < B_ * (NP1 + M_)) {
        int b = u / (NP1 + M_), r = u % (NP1 + M_);
        float lam = expf(eps_p[0]) + 0.03f;
        float s = (alpha_p[0] - 1.0f) / lam;
        size_t idx;
        if (r < NP1) idx = ((size_t)b * MP1 + M_) * SH_STRIDE + r;
        else         idx = ((size_t)b * MP1 + (r - NP1)) * SH_STRIDE + N_;
        Sh[idx] = (_Float16)s;
    }
}

// ---------------- fp32-path fill (tier 3) ----------------
__global__ __launch_bounds__(256) void fill_edges_f32(
    float* __restrict__ Sout, const float* __restrict__ alpha_p, const float* __restrict__ eps_p)
{
    int t = blockIdx.x * 256 + threadIdx.x;
    if (t >= B_ * (NP1 + M_)) return;
    int b = t / (NP1 + M_), r = t % (NP1 + M_);
    float lam = expf(eps_p[0]) + 0.03f;
    float s = (alpha_p[0] - 1.0f) / lam;
    size_t idx;
    if (r < NP1) idx = ((size_t)b * MP1 + M_) * NP1 + r;
    else         idx = ((size_t)b * MP1 + (r - NP1)) * NP1 + N_;
    Sout[idx] = s;
}

// ================= fp16 path: fused row-update + column partials =================
// 8 rows per block (4 waves x 2 rows). Max-free LSE; partials include exp(v_old).
__global__ __launch_bounds__(256) void fused_rowcol_h(
    const _Float16* __restrict__ Sh, const float* __restrict__ v,
    float* __restrict__ ps)
{
    int b = blockIdx.y;
    int chunk = blockIdx.x;      // 0..128
    int tid = threadIdx.x;
    int lane = tid & 63;
    int w = tid >> 6;

    __shared__ float red[4][17][64];   // [wave][e][lane]

    const float* vb = v + (size_t)b * VSTR;
    float vreg[16];
    {
        float4 v0 = *(const float4*)(vb + lane * 8);
        float4 v1 = *(const float4*)(vb + lane * 8 + 4);
        float4 v2 = *(const float4*)(vb + 512 + lane * 8);
        float4 v3 = *(const float4*)(vb + 512 + lane * 8 + 4);
        vreg[0]=v0.x; vreg[1]=v0.y; vreg[2]=v0.z; vreg[3]=v0.w;
        vreg[4]=v1.x; vreg[5]=v1.y; vreg[6]=v1.z; vreg[7]=v1.w;
        vreg[8]=v2.x; vreg[9]=v2.y; vreg[10]=v2.z; vreg[11]=v2.w;
        vreg[12]=v3.x; vreg[13]=v3.y; vreg[14]=v3.z; vreg[15]=v3.w;
    }
    float v1024 = vb[1024];

    float creg[16] = {};
    float creg16 = 0.f;

    #pragma unroll
    for (int rr = 0; rr < 2; ++rr) {
        int i = chunk * 8 + w * 2 + rr;
        if (i < MP1) {
            const _Float16* row = Sh + ((size_t)b * MP1 + i) * SH_STRIDE;
            h16x8 h0 = *(const h16x8*)(row + lane * 8);
            h16x8 h1 = *(const h16x8*)(row + 512 + lane * 8);
            float et[16];
            float rs = 0.f;
            #pragma unroll
            for (int e = 0; e < 8; ++e) { et[e] = expf((float)h0[e] + vreg[e]); rs += et[e]; }
            #pragma unroll
            for (int e = 0; e < 8; ++e) { et[8 + e] = expf((float)h1[e] + vreg[8 + e]); rs += et[8 + e]; }
            float et16 = 0.f;
            if (lane == 0) { et16 = expf((float)row[1024] + v1024); rs += et16; }
            #pragma unroll
            for (int o = 32; o; o >>= 1) rs += __shfl_xor(rs, o);
            float A = (i == M_) ? 0.5f : (1.0f / 2048.0f);   // exp(log_a)
            float scale = A / rs;                             // exp(u_i)
            #pragma unroll
            for (int e = 0; e < 16; ++e) creg[e] += et[e] * scale;
            creg16 += et16 * scale;                           // nonzero only on lane 0
        }
    }

    #pragma unroll
    for (int e = 0; e < 16; ++e) red[w][e][lane] = creg[e];
    red[w][16][lane] = creg16;
    __syncthreads();

    float* out = ps + ((size_t)chunk * B_ + b) * NP1;
    for (int j = tid; j < 1024; j += 256) {
        int lane_j = (j < 512) ? (j >> 3) : ((j - 512) >> 3);
        int e_j    = (j < 512) ? (j & 7) : (8 + (j & 7));
        float s = red[0][e_j][lane_j] + red[1][e_j][lane_j]
                + red[2][e_j][lane_j] + red[3][e_j][lane_j];
        out[j] = s;
    }
    if (tid == 0) {
        float s = red[0][16][0] + red[1][16][0] + red[2][16][0] + red[3][16][0];
        out[1024] = s;
    }
}

// combine 129 chunk partials -> v, 2 threads per column.
// colsum = sum_i exp(s+u+v_old) => v_new = v_old + lb - log(colsum)
__global__ __launch_bounds__(256) void col_pass2_f(
    const float* __restrict__ ps, float* __restrict__ v)
{
    int t = blockIdx.x * 256 + threadIdx.x;
    int j = t >> 1, half = t & 1;
    if (j >= NP1) return;
    int b = blockIdx.y;
    float s = 0.f;
    int c0 = half ? 65 : 0;
    int c1 = half ? NCH : 65;
    for (int c = c0; c < c1; ++c) s += ps[((size_t)c * B_ + b) * NP1 + j];
    s += __shfl_xor(s, 1);
    if (half == 0) {
        float lb = (j == N_) ? LOG_HALF : LOG_NORM;
        size_t idx = (size_t)b * VSTR + j;
        v[idx] = v[idx] + lb - logf(s);
    }
}

// fused final row pass + finalize: vectorized h16x8 loads, float4 stores
__global__ __launch_bounds__(256) void row_final_h(
    const _Float16* __restrict__ Sh, const float* __restrict__ v, float* __restrict__ out)
{
    int wv = (blockIdx.x * 256 + threadIdx.x) >> 6;
    int lane = threadIdx.x & 63;
    if (wv >= B_ * MP1) return;
    int b = wv / MP1, i = wv % MP1;
    const _Float16* row = Sh + ((size_t)b * MP1 + i) * SH_STRIDE;
    float* orow = out + ((size_t)b * MP1 + i) * NP1;
    const float* vb = v + (size_t)b * VSTR;
    float vreg[16];
    {
        float4 v0 = *(const float4*)(vb + lane * 8);
        float4 v1 = *(const float4*)(vb + lane * 8 + 4);
        float4 v2 = *(const float4*)(vb + 512 + lane * 8);
        float4 v3 = *(const float4*)(vb + 512 + lane * 8 + 4);
        vreg[0]=v0.x; vreg[1]=v0.y; vreg[2]=v0.z; vreg[3]=v0.w;
        vreg[4]=v1.x; vreg[5]=v1.y; vreg[6]=v1.z; vreg[7]=v1.w;
        vreg[8]=v2.x; vreg[9]=v2.y; vreg[10]=v2.z; vreg[11]=v2.w;
        vreg[12]=v3.x; vreg[13]=v3.y; vreg[14]=v3.z; vreg[15]=v3.w;
    }
    h16x8 h0 = *(const h16x8*)(row + lane * 8);
    h16x8 h1 = *(const h16x8*)(row + 512 + lane * 8);
    float et[16];
    float sm = 0.f;
    #pragma unroll
    for (int e = 0; e < 8; ++e) { et[e] = expf((float)h0[e] + vreg[e]); sm += et[e]; }
    #pragma unroll
    for (int e = 0; e < 8; ++e) { et[8 + e] = expf((float)h1[e] + vreg[8 + e]); sm += et[8 + e]; }
    float e1024 = 0.f;
    if (lane == 0) { e1024 = expf((float)row[1024] + vb[1024]); sm += e1024; }
    #pragma unroll
    for (int o = 32; o; o >>= 1) sm += __shfl_xor(sm, o);
    float A = (i == M_) ? 0.5f : (1.0f / 2048.0f);
    float scale = (A / sm) * 2048.0f;
    float4 o0 = {et[0]*scale,  et[1]*scale,  et[2]*scale,  et[3]*scale};
    float4 o1 = {et[4]*scale,  et[5]*scale,  et[6]*scale,  et[7]*scale};
    float4 o2 = {et[8]*scale,  et[9]*scale,  et[10]*scale, et[11]*scale};
    float4 o3 = {et[12]*scale, et[13]*scale, et[14]*scale, et[15]*scale};
    *(float4*)(orow + lane * 8)       = o0;
    *(float4*)(orow + lane * 8 + 4)   = o1;
    *(float4*)(orow + 512 + lane * 8)     = o2;
    *(float4*)(orow + 512 + lane * 8 + 4) = o3;
    if (lane == 0) orow[1024] = e1024 * scale;
}

// ================= fp32 fallback kernels (tier 3, S in d_out) =================

__global__ __launch_bounds__(256) void row_pass_kernel(
    const float* __restrict__ S, const float* __restrict__ v, float* __restrict__ u)
{
    int w = (blockIdx.x * 256 + threadIdx.x) >> 6;
    int lane = threadIdx.x & 63;
    if (w >= B_ * MP1) return;
    int b = w / MP1, i = w % MP1;
    const float* row = S + ((size_t)b * MP1 + i) * NP1;
    const float* vb = v + b * NP1;
    float sm = 0.f;
    #pragma unroll
    for (int q = 0; q < 17; ++q) {
        int j = lane + q * 64;
        if (j < NP1) sm += expf(row[j] + vb[j]);
    }
    #pragma unroll
    for (int o = 32; o; o >>= 1) sm += __shfl_xor(sm, o);
    if (lane == 0) {
        float la = (i == M_) ? LOG_HALF : LOG_NORM;
        u[b * MP1 + i] = la - logf(sm);
    }
}

__global__ __launch_bounds__(256) void col_pass1_kernel(
    const float* __restrict__ S, const float* __restrict__ u,
    float* __restrict__ pm, float* __restrict__ ps)
{
    int j = blockIdx.x * 256 + threadIdx.x;
    int b = blockIdx.z;
    int i0 = blockIdx.y * 128;
    int i1 = min(i0 + 128, MP1);
    if (j >= NP1) return;
    const float* p  = S + ((size_t)b * MP1 + i0) * NP1 + j;
    const float* ub = u + b * MP1;
    float sm = 0.f;
    for (int i = i0; i < i1; ++i) {
        sm += expf(*p + ub[i]);
        p += NP1;
    }
    int idx = (blockIdx.y * B_ + b) * NP1 + j;
    pm[idx] = 0.f;
    ps[idx] = sm;
}

__global__ __launch_bounds__(256) void col_pass2_kernel(
    const float* __restrict__ pm, const float* __restrict__ ps, float* __restrict__ v)
{
    int j = blockIdx.x * 256 + threadIdx.x;
    int b = blockIdx.y;
    if (j >= NP1) return;
    float Ssum = 0.f;
    #pragma unroll
    for (int c = 0; c < 9; ++c) Ssum += ps[(c * B_ + b) * NP1 + j];
    float lb = (j == N_) ? LOG_HALF : LOG_NORM;
    v[b * NP1 + j] = lb - logf(Ssum);
}

__global__ __launch_bounds__(256) void row_final_kernel(
    float* __restrict__ S, const float* __restrict__ v)
{
    int w = (blockIdx.x * 256 + threadIdx.x) >> 6;
    int lane = threadIdx.x & 63;
    if (w >= B_ * MP1) return;
    int b = w / MP1, i = w % MP1;
    float* row = S + ((size_t)b * MP1 + i) * NP1;
    const float* vb = v + b * NP1;
    float et[17];
    float sm = 0.f;
    #pragma unroll
    for (int q = 0; q < 17; ++q) {
        int j = lane + q * 64;
        float e = 0.f;
        if (j < NP1) e = expf(row[j] + vb[j]);
        et[q] = e;
        sm += e;
    }
    #pragma unroll
    for (int o = 32; o; o >>= 1) sm += __shfl_xor(sm, o);
    float A = (i == M_) ? 0.5f : (1.0f / 2048.0f);
    float scale = (A / sm) * 2048.0f;
    #pragma unroll
    for (int q = 0; q < 17; ++q) {
        int j = lane + q * 64;
        if (j < NP1) row[j] = et[q] * scale;
    }
}

__global__ __launch_bounds__(256) void zero_kernel(float* __restrict__ p, int n)
{
    int i = blockIdx.x * 256 + threadIdx.x;
    if (i < n) p[i] = 0.f;
}

extern "C" void kernel_launch(void* const* d_in, const int* in_sizes, int n_in,
                              void* d_out, int out_size, void* d_ws, size_t ws_size,
                              hipStream_t stream)
{
    const float* tf    = (const float*)d_in[0];
    const float* df    = (const float*)d_in[1];
    const float* tl    = (const float*)d_in[2];
    const float* dl    = (const float*)d_in[3];
    const float* alpha = (const float*)d_in[4];
    const float* eps   = (const float*)d_in[5];
    float* out = (float*)d_out;

    const size_t bf_one    = (size_t)B_ * M_ * D_ * 2;            // one bf16 feature matrix
    const size_t sh_bytes  = (size_t)B_ * MP1 * SH_STRIDE * 2;    // fp16 S
    const size_t small_f   = (size_t)B_ * M_ * 2 + (size_t)B_ * VSTR;  // inv1,inv2,v floats
    const size_t need_pre  = 2 * bf_one + sh_bytes + small_f * 4 + 512;
    const size_t need_mid  = sh_bytes + small_f * 4 + 512;

    int rowblocks = (B_ * MP1 + 3) / 4;
    int initblocks = (B_ * VSTR + B_ * (NP1 + M_) + 255) / 256;

    if (ws_size >= need_pre) {
        unsigned short* tfh = (unsigned short*)d_ws;
        unsigned short* dfh = tfh + (size_t)B_ * M_ * D_;
        _Float16* Sh = (_Float16*)((char*)d_ws + 2 * bf_one);
        float* fbase = (float*)((char*)d_ws + ((2 * bf_one + sh_bytes + 255) & ~(size_t)255));
        float* inv1 = fbase;
        float* inv2 = inv1 + B_ * M_;
        float* v    = inv2 + B_ * N_;
        float* ps   = out;

        init_h_kernel<<<initblocks, 256, 0, stream>>>(v, Sh, alpha, eps);
        norms_kernel_t<true><<<(B_ * 2048) / 4, 256, 0, stream>>>(tf, df, inv1, inv2, tfh, dfh);
        gemm_s_kernel<2><<<1024, 256, 0, stream>>>(tfh, dfh, tl, dl, inv1, inv2, eps, Sh);

        for (int it = 0; it < NUM_SINK; ++it) {
            fused_rowcol_h<<<dim3(NCH, B_), 256, 0, stream>>>(Sh, v, ps);
            col_pass2_f<<<dim3(9, B_), 256, 0, stream>>>(ps, v);
        }
        row_final_h<<<rowblocks, 256, 0, stream>>>(Sh, v, out);
    } else if (ws_size >= need_mid) {
        _Float16* Sh = (_Float16*)d_ws;
        float* fbase = (float*)((char*)d_ws + ((sh_bytes + 255) & ~(size_t)255));
        float* inv1 = fbase;
        float* inv2 = inv1 + B_ * M_;
        float* v    = inv2 + B_ * N_;
        float* ps   = out;

        init_h_kernel<<<initblocks, 256, 0, stream>>>(v, Sh, alpha, eps);
        norms_kernel_t<false><<<(B_ * 2048) / 4, 256, 0, stream>>>(tf, df, inv1, inv2, nullptr, nullptr);
        gemm_s_kernel<1><<<1024, 256, 0, stream>>>(tf, df, tl, dl, inv1, inv2, eps, Sh);

        for (int it = 0; it < NUM_SINK; ++it) {
            fused_rowcol_h<<<dim3(NCH, B_), 256, 0, stream>>>(Sh, v, ps);
            col_pass2_f<<<dim3(9, B_), 256, 0, stream>>>(ps, v);
        }
        row_final_h<<<rowblocks, 256, 0, stream>>>(Sh, v, out);
    } else {
        float* S = out;
        float* ws = (float*)d_ws;
        float* inv1 = ws;
        float* inv2 = inv1 + B_ * M_;
        float* u    = inv2 + B_ * N_;
        float* v    = u + B_ * MP1;
        float* pm   = v + B_ * NP1;
        float* ps   = pm + 9 * B_ * NP1;

        zero_kernel<<<(B_ * NP1 + 255) / 256, 256, 0, stream>>>(v, B_ * NP1);
        norms_kernel_t<false><<<(B_ * 2048) / 4, 256, 0, stream>>>(tf, df, inv1, inv2, nullptr, nullptr);
        gemm_s_kernel<0><<<1024, 256, 0, stream>>>(tf, df, tl, dl, inv1, inv2, eps, S);
        fill_edges_f32<<<(B_ * (NP1 + M_) + 255) / 256, 256, 0, stream>>>(S, alpha, eps);

        for (int it = 0; it < NUM_SINK; ++it) {
            row_pass_kernel<<<rowblocks, 256, 0, stream>>>(S, v, u);
            col_pass1_kernel<<<dim3(5, 9, 16), 256, 0, stream>>>(S, u, pm, ps);
            col_pass2_kernel<<<dim3(5, 16), 256, 0, stream>>>(pm, ps, v);
        }
        row_final_kernel<<<rowblocks, 256, 0, stream>>>(S, v);
    }
}

// Round 7
// 222.098 us; speedup vs baseline: 1.6228x; 1.6228x over previous
//
#include <hip/hip_runtime.h>
#include <math.h>

#define B_ 16
#define M_ 1024
#define N_ 1024
#define D_ 512
#define MP1 1025
#define NP1 1025
#define NUM_SINK 8
#define BK 64
#define SH_STRIDE 1032   // fp16 row stride (elements), 16B-aligned rows
#define VSTR 1028        // v stride (floats), 16B-aligned
#define NCH 65           // chunks of 16 rows (64*16=1024 + 1 chunk for row 1024)
// log(1/2048), log(1/2)
#define LOG_NORM (-7.6246189861593985f)
#define LOG_HALF (-0.6931471805599453f)

typedef __attribute__((ext_vector_type(8))) short bf16x8;
typedef __attribute__((ext_vector_type(4))) float f32x4;
typedef __attribute__((ext_vector_type(8))) _Float16 h16x8;

__device__ inline short f2bf(float x) {
    unsigned u = __builtin_bit_cast(unsigned, x);
    u = (u + 0x7FFFu + ((u >> 16) & 1u)) >> 16;
    return (short)u;
}

__device__ inline void gload16(const void* g, void* l) {
    __builtin_amdgcn_global_load_lds(
        (const __attribute__((address_space(1))) unsigned int*)g,
        (__attribute__((address_space(3))) unsigned int*)l, 16, 0, 0);
}

// ---------------- norms + optional bf16 conversion: one wave per feature row ----------------
template<bool CONV>
__global__ __launch_bounds__(256) void norms_kernel_t(
    const float* __restrict__ tf, const float* __restrict__ df,
    float* __restrict__ inv1, float* __restrict__ inv2,
    unsigned short* __restrict__ tfh, unsigned short* __restrict__ dfh)
{
    int w = (blockIdx.x * 256 + threadIdx.x) >> 6;
    int lane = threadIdx.x & 63;
    if (w >= B_ * 2048) return;
    int b = w >> 11;
    int rr = w & 2047;
    const float* src;
    float* dst;
    unsigned short* dsth;
    if (rr < M_) { src = tf + ((size_t)b * M_ + rr) * D_;        dst = inv1 + b * M_ + rr;
                   dsth = CONV ? tfh + ((size_t)b * M_ + rr) * D_ : nullptr; }
    else         { src = df + ((size_t)b * N_ + (rr - M_)) * D_; dst = inv2 + b * N_ + (rr - M_);
                   dsth = CONV ? dfh + ((size_t)b * N_ + (rr - M_)) * D_ : nullptr; }
    float4 x = *(const float4*)(src + lane * 4);
    float4 y = *(const float4*)(src + 256 + lane * 4);
    if (CONV) {
        ushort4 hx, hy;
        hx.x = (unsigned short)f2bf(x.x); hx.y = (unsigned short)f2bf(x.y);
        hx.z = (unsigned short)f2bf(x.z); hx.w = (unsigned short)f2bf(x.w);
        hy.x = (unsigned short)f2bf(y.x); hy.y = (unsigned short)f2bf(y.y);
        hy.z = (unsigned short)f2bf(y.z); hy.w = (unsigned short)f2bf(y.w);
        *(ushort4*)(dsth + lane * 4) = hx;
        *(ushort4*)(dsth + 256 + lane * 4) = hy;
    }
    float ss = x.x*x.x + x.y*x.y + x.z*x.z + x.w*x.w
             + y.x*y.x + y.y*y.y + y.z*y.z + y.w*y.w;
    #pragma unroll
    for (int o = 32; o; o >>= 1) ss += __shfl_xor(ss, o);
    if (lane == 0) *dst = 1.0f / sqrtf(ss);
}

// ---------------- MFMA GEMM + epilogue: S = (cos*mask - 1)/lambda ----------------
// MODE 0: fp32 out, f2bf reg-staging.  MODE 1: fp16 out, f2bf reg-staging.
// MODE 2: fp16 out, global_load_lds from pre-converted bf16 (swizzled source).
template<int MODE>
__global__ __launch_bounds__(256) void gemm_s_kernel(
    const void* __restrict__ A, const void* __restrict__ Bm,
    const float* __restrict__ tl, const float* __restrict__ dl,
    const float* __restrict__ inv1, const float* __restrict__ inv2,
    const float* __restrict__ eps_p, void* __restrict__ Sout)
{
    __shared__ __align__(16) unsigned short As[128 * BK];
    __shared__ __align__(16) unsigned short Bs[128 * BK];

    int flat = blockIdx.x;
    int swz = (flat & 7) * 128 + (flat >> 3);
    int jb = swz & 7, ib = (swz >> 3) & 7;
    int b  = swz >> 6;
    int i0 = ib * 128;
    int j0 = jb * 128;

    int tid  = threadIdx.x;
    int lane = tid & 63;
    int w    = tid >> 6;
    int wm   = w >> 1, wn = w & 1;

    f32x4 acc[4][4] = {};

    if constexpr (MODE == 2) {
        const unsigned short* Ah = (const unsigned short*)A  + (size_t)b * M_ * D_;
        const unsigned short* Bh = (const unsigned short*)Bm + (size_t)b * N_ * D_;
        int gcol = ((lane & 7) ^ (lane >> 3)) << 3;   // pre-swizzled source element offset
        int rloc = lane >> 3;
        for (int k0 = 0; k0 < D_; k0 += BK) {
            #pragma unroll
            for (int c = 0; c < 4; ++c) {
                int r = (w * 4 + c) * 8 + rloc;
                gload16(Ah + (size_t)(i0 + r) * D_ + k0 + gcol,
                        (char*)As + (w * 4 + c) * 1024 + lane * 16);
                gload16(Bh + (size_t)(j0 + r) * D_ + k0 + gcol,
                        (char*)Bs + (w * 4 + c) * 1024 + lane * 16);
            }
            __syncthreads();
            #pragma unroll
            for (int ks = 0; ks < 2; ++ks) {
                int kb = ks * 64 + ((lane >> 4) << 4);
                bf16x8 af[4], bfr[4];
                #pragma unroll
                for (int m = 0; m < 4; ++m) {
                    int ra = wm * 64 + m * 16 + (lane & 15);
                    af[m] = *(const bf16x8*)((const char*)As + ra * 128 + (kb ^ ((ra & 7) << 4)));
                    int rb = wn * 64 + m * 16 + (lane & 15);
                    bfr[m] = *(const bf16x8*)((const char*)Bs + rb * 128 + (kb ^ ((rb & 7) << 4)));
                }
                #pragma unroll
                for (int m = 0; m < 4; ++m)
                    #pragma unroll
                    for (int n = 0; n < 4; ++n)
                        acc[m][n] = __builtin_amdgcn_mfma_f32_16x16x32_bf16(af[m], bfr[n], acc[m][n], 0, 0, 0);
            }
            __syncthreads();
        }
    } else {
        const float* Ab = (const float*)A  + (size_t)b * M_ * D_;
        const float* Bb = (const float*)Bm + (size_t)b * N_ * D_;
        int seg   = tid & 7;
        int rbase = tid >> 3;
        for (int k0 = 0; k0 < D_; k0 += BK) {
            #pragma unroll
            for (int rr = 0; rr < 4; ++rr) {
                int r = rbase + rr * 32;
                int colx = (seg * 16) ^ ((r & 7) << 4);
                {
                    const float* pa = Ab + (size_t)(i0 + r) * D_ + k0 + seg * 8;
                    float4 a0 = *(const float4*)pa;
                    float4 a1 = *(const float4*)(pa + 4);
                    bf16x8 hv;
                    hv[0] = f2bf(a0.x); hv[1] = f2bf(a0.y); hv[2] = f2bf(a0.z); hv[3] = f2bf(a0.w);
                    hv[4] = f2bf(a1.x); hv[5] = f2bf(a1.y); hv[6] = f2bf(a1.z); hv[7] = f2bf(a1.w);
                    *(bf16x8*)((char*)As + r * 128 + colx) = hv;
                }
                {
                    const float* pb = Bb + (size_t)(j0 + r) * D_ + k0 + seg * 8;
                    float4 b0 = *(const float4*)pb;
                    float4 b1 = *(const float4*)(pb + 4);
                    bf16x8 hv;
                    hv[0] = f2bf(b0.x); hv[1] = f2bf(b0.y); hv[2] = f2bf(b0.z); hv[3] = f2bf(b0.w);
                    hv[4] = f2bf(b1.x); hv[5] = f2bf(b1.y); hv[6] = f2bf(b1.z); hv[7] = f2bf(b1.w);
                    *(bf16x8*)((char*)Bs + r * 128 + colx) = hv;
                }
            }
            __syncthreads();
            #pragma unroll
            for (int ks = 0; ks < 2; ++ks) {
                int kb = ks * 64 + ((lane >> 4) << 4);
                bf16x8 af[4], bfr[4];
                #pragma unroll
                for (int m = 0; m < 4; ++m) {
                    int ra = wm * 64 + m * 16 + (lane & 15);
                    af[m] = *(const bf16x8*)((const char*)As + ra * 128 + (kb ^ ((ra & 7) << 4)));
                    int rb = wn * 64 + m * 16 + (lane & 15);
                    bfr[m] = *(const bf16x8*)((const char*)Bs + rb * 128 + (kb ^ ((rb & 7) << 4)));
                }
                #pragma unroll
                for (int m = 0; m < 4; ++m)
                    #pragma unroll
                    for (int n = 0; n < 4; ++n)
                        acc[m][n] = __builtin_amdgcn_mfma_f32_16x16x32_bf16(af[m], bfr[n], acc[m][n], 0, 0, 0);
            }
            __syncthreads();
        }
    }

    float lam = expf(eps_p[0]) + 0.03f;
    float inv_lam = 1.0f / lam;
    int crow0 = i0 + wm * 64;
    int ccol0 = j0 + wn * 64;
    int rlane = lane >> 4;
    int clane = lane & 15;

    float invb_[4], dlx_[4], dly_[4];
    #pragma unroll
    for (int n = 0; n < 4; ++n) {
        int j = ccol0 + n * 16 + clane;
        invb_[n] = inv2[b * N_ + j];
        dlx_[n]  = dl[((size_t)b * N_ + j) * 2 + 0];
        dly_[n]  = dl[((size_t)b * N_ + j) * 2 + 1];
    }
    #pragma unroll
    for (int m = 0; m < 4; ++m) {
        #pragma unroll
        for (int reg = 0; reg < 4; ++reg) {
            int i = crow0 + m * 16 + rlane * 4 + reg;
            float inva = inv1[b * M_ + i];
            float tlx  = tl[((size_t)b * M_ + i) * 2 + 0];
            float tly  = tl[((size_t)b * M_ + i) * 2 + 1];
            #pragma unroll
            for (int n = 0; n < 4; ++n) {
                float cosv = acc[m][n][reg] * inva * invb_[n];
                float dx = tlx - dlx_[n];
                float dy = tly - dly_[n];
                float msk = (sqrtf(dx * dx + dy * dy) <= 0.3f) ? 1.0f : 0.0f;
                float val = (cosv * msk - 1.0f) * inv_lam;
                int col = ccol0 + n * 16 + clane;
                if (MODE >= 1) {
                    _Float16* Srow = (_Float16*)Sout + ((size_t)b * MP1 + i) * SH_STRIDE;
                    Srow[col] = (_Float16)val;
                } else {
                    float* Srow = (float*)Sout + ((size_t)b * MP1 + i) * NP1;
                    Srow[col] = val;
                }
            }
        }
    }
}

// ---------------- init: zero v + fill fp16 dustbin row/col ----------------
__global__ __launch_bounds__(256) void init_h_kernel(
    float* __restrict__ v, _Float16* __restrict__ Sh,
    const float* __restrict__ alpha_p, const float* __restrict__ eps_p)
{
    int t = blockIdx.x * 256 + threadIdx.x;
    if (t < B_ * VSTR) v[t] = 0.f;
    int u = t - B_ * VSTR;
    if (u >= 0 && u < B_ * (NP1 + M_)) {
        int b = u / (NP1 + M_), r = u % (NP1 + M_);
        float lam = expf(eps_p[0]) + 0.03f;
        float s = (alpha_p[0] - 1.0f) / lam;
        size_t idx;
        if (r < NP1) idx = ((size_t)b * MP1 + M_) * SH_STRIDE + r;
        else         idx = ((size_t)b * MP1 + (r - NP1)) * SH_STRIDE + N_;
        Sh[idx] = (_Float16)s;
    }
}

// ---------------- fp32-path fill (tier 3) ----------------
__global__ __launch_bounds__(256) void fill_edges_f32(
    float* __restrict__ Sout, const float* __restrict__ alpha_p, const float* __restrict__ eps_p)
{
    int t = blockIdx.x * 256 + threadIdx.x;
    if (t >= B_ * (NP1 + M_)) return;
    int b = t / (NP1 + M_), r = t % (NP1 + M_);
    float lam = expf(eps_p[0]) + 0.03f;
    float s = (alpha_p[0] - 1.0f) / lam;
    size_t idx;
    if (r < NP1) idx = ((size_t)b * MP1 + M_) * NP1 + r;
    else         idx = ((size_t)b * MP1 + (r - NP1)) * NP1 + N_;
    Sout[idx] = s;
}

// ================= fp16 path: fused row-update + column partials =================
// 16 rows per block (4 waves x 4 rows), rows preloaded to hide latency.
// Max-free LSE; partials include exp(v_old); col_pass2_f compensates with +v_old.
__global__ __launch_bounds__(256) void fused_rowcol_h(
    const _Float16* __restrict__ Sh, const float* __restrict__ v,
    float* __restrict__ ps)
{
    int b = blockIdx.y;
    int chunk = blockIdx.x;      // 0..64
    int tid = threadIdx.x;
    int lane = tid & 63;
    int w = tid >> 6;

    __shared__ float red[4][64][17];   // [wave][lane][e] — stride-17 words: conflict-free

    const float* vb = v + (size_t)b * VSTR;
    float vreg[16];
    {
        float4 v0 = *(const float4*)(vb + lane * 8);
        float4 v1 = *(const float4*)(vb + lane * 8 + 4);
        float4 v2 = *(const float4*)(vb + 512 + lane * 8);
        float4 v3 = *(const float4*)(vb + 512 + lane * 8 + 4);
        vreg[0]=v0.x; vreg[1]=v0.y; vreg[2]=v0.z; vreg[3]=v0.w;
        vreg[4]=v1.x; vreg[5]=v1.y; vreg[6]=v1.z; vreg[7]=v1.w;
        vreg[8]=v2.x; vreg[9]=v2.y; vreg[10]=v2.z; vreg[11]=v2.w;
        vreg[12]=v3.x; vreg[13]=v3.y; vreg[14]=v3.z; vreg[15]=v3.w;
    }
    float v1024 = vb[1024];

    int ibase = chunk * 16 + w * 4;

    // preload all 4 rows (8 independent 16B loads in flight)
    h16x8 h0[4], h1[4];
    #pragma unroll
    for (int rr = 0; rr < 4; ++rr) {
        int i = ibase + rr;
        if (i < MP1) {
            const _Float16* row = Sh + ((size_t)b * MP1 + i) * SH_STRIDE;
            h0[rr] = *(const h16x8*)(row + lane * 8);
            h1[rr] = *(const h16x8*)(row + 512 + lane * 8);
        }
    }

    float creg[16] = {};
    float creg16 = 0.f;

    #pragma unroll
    for (int rr = 0; rr < 4; ++rr) {
        int i = ibase + rr;
        if (i < MP1) {
            float et[16];
            float rs = 0.f;
            #pragma unroll
            for (int e = 0; e < 8; ++e) { et[e] = __expf((float)h0[rr][e] + vreg[e]); rs += et[e]; }
            #pragma unroll
            for (int e = 0; e < 8; ++e) { et[8 + e] = __expf((float)h1[rr][e] + vreg[8 + e]); rs += et[8 + e]; }
            float et16 = 0.f;
            if (lane == 0) {
                et16 = __expf((float)Sh[((size_t)b * MP1 + i) * SH_STRIDE + 1024] + v1024);
                rs += et16;
            }
            #pragma unroll
            for (int o = 32; o; o >>= 1) rs += __shfl_xor(rs, o);
            float A = (i == M_) ? 0.5f : (1.0f / 2048.0f);   // exp(log_a)
            float scale = A / rs;                             // exp(u_i)
            #pragma unroll
            for (int e = 0; e < 16; ++e) creg[e] += et[e] * scale;
            creg16 += et16 * scale;                           // nonzero only on lane 0
        }
    }

    #pragma unroll
    for (int e = 0; e < 16; ++e) red[w][lane][e] = creg[e];
    red[w][lane][16] = creg16;
    __syncthreads();

    float* out = ps + ((size_t)chunk * B_ + b) * NP1;
    for (int j = tid; j < 1024; j += 256) {
        int lane_j = (j < 512) ? (j >> 3) : ((j - 512) >> 3);
        int e_j    = (j < 512) ? (j & 7) : (8 + (j & 7));
        float s = red[0][lane_j][e_j] + red[1][lane_j][e_j]
                + red[2][lane_j][e_j] + red[3][lane_j][e_j];
        out[j] = s;
    }
    if (tid == 0) {
        float s = red[0][0][16] + red[1][0][16] + red[2][0][16] + red[3][0][16];
        out[1024] = s;
    }
}

// combine 65 chunk partials -> v.
// colsum = sum_i exp(s+u+v_old) => v_new = v_old + lb - log(colsum)
__global__ __launch_bounds__(256) void col_pass2_f(
    const float* __restrict__ ps, float* __restrict__ v)
{
    int j = blockIdx.x * 256 + threadIdx.x;
    int b = blockIdx.y;
    if (j >= NP1) return;
    float s = 0.f;
    for (int c = 0; c < NCH; ++c) s += ps[((size_t)c * B_ + b) * NP1 + j];
    float lb = (j == N_) ? LOG_HALF : LOG_NORM;
    size_t idx = (size_t)b * VSTR + j;
    v[idx] = v[idx] + lb - __logf(s);
}

// fused final row pass + finalize: vectorized h16x8 loads, float4 stores
__global__ __launch_bounds__(256) void row_final_h(
    const _Float16* __restrict__ Sh, const float* __restrict__ v, float* __restrict__ out)
{
    int wv = (blockIdx.x * 256 + threadIdx.x) >> 6;
    int lane = threadIdx.x & 63;
    if (wv >= B_ * MP1) return;
    int b = wv / MP1, i = wv % MP1;
    const _Float16* row = Sh + ((size_t)b * MP1 + i) * SH_STRIDE;
    float* orow = out + ((size_t)b * MP1 + i) * NP1;
    const float* vb = v + (size_t)b * VSTR;
    float vreg[16];
    {
        float4 v0 = *(const float4*)(vb + lane * 8);
        float4 v1 = *(const float4*)(vb + lane * 8 + 4);
        float4 v2 = *(const float4*)(vb + 512 + lane * 8);
        float4 v3 = *(const float4*)(vb + 512 + lane * 8 + 4);
        vreg[0]=v0.x; vreg[1]=v0.y; vreg[2]=v0.z; vreg[3]=v0.w;
        vreg[4]=v1.x; vreg[5]=v1.y; vreg[6]=v1.z; vreg[7]=v1.w;
        vreg[8]=v2.x; vreg[9]=v2.y; vreg[10]=v2.z; vreg[11]=v2.w;
        vreg[12]=v3.x; vreg[13]=v3.y; vreg[14]=v3.z; vreg[15]=v3.w;
    }
    h16x8 h0 = *(const h16x8*)(row + lane * 8);
    h16x8 h1 = *(const h16x8*)(row + 512 + lane * 8);
    float et[16];
    float sm = 0.f;
    #pragma unroll
    for (int e = 0; e < 8; ++e) { et[e] = __expf((float)h0[e] + vreg[e]); sm += et[e]; }
    #pragma unroll
    for (int e = 0; e < 8; ++e) { et[8 + e] = __expf((float)h1[e] + vreg[8 + e]); sm += et[8 + e]; }
    float e1024 = 0.f;
    if (lane == 0) { e1024 = __expf((float)row[1024] + vb[1024]); sm += e1024; }
    #pragma unroll
    for (int o = 32; o; o >>= 1) sm += __shfl_xor(sm, o);
    float A = (i == M_) ? 0.5f : (1.0f / 2048.0f);
    float scale = (A / sm) * 2048.0f;
    float4 o0 = {et[0]*scale,  et[1]*scale,  et[2]*scale,  et[3]*scale};
    float4 o1 = {et[4]*scale,  et[5]*scale,  et[6]*scale,  et[7]*scale};
    float4 o2 = {et[8]*scale,  et[9]*scale,  et[10]*scale, et[11]*scale};
    float4 o3 = {et[12]*scale, et[13]*scale, et[14]*scale, et[15]*scale};
    *(float4*)(orow + lane * 8)       = o0;
    *(float4*)(orow + lane * 8 + 4)   = o1;
    *(float4*)(orow + 512 + lane * 8)     = o2;
    *(float4*)(orow + 512 + lane * 8 + 4) = o3;
    if (lane == 0) orow[1024] = e1024 * scale;
}

// ================= fp32 fallback kernels (tier 3, S in d_out) =================

__global__ __launch_bounds__(256) void row_pass_kernel(
    const float* __restrict__ S, const float* __restrict__ v, float* __restrict__ u)
{
    int w = (blockIdx.x * 256 + threadIdx.x) >> 6;
    int lane = threadIdx.x & 63;
    if (w >= B_ * MP1) return;
    int b = w / MP1, i = w % MP1;
    const float* row = S + ((size_t)b * MP1 + i) * NP1;
    const float* vb = v + b * NP1;
    float sm = 0.f;
    #pragma unroll
    for (int q = 0; q < 17; ++q) {
        int j = lane + q * 64;
        if (j < NP1) sm += expf(row[j] + vb[j]);
    }
    #pragma unroll
    for (int o = 32; o; o >>= 1) sm += __shfl_xor(sm, o);
    if (lane == 0) {
        float la = (i == M_) ? LOG_HALF : LOG_NORM;
        u[b * MP1 + i] = la - logf(sm);
    }
}

__global__ __launch_bounds__(256) void col_pass1_kernel(
    const float* __restrict__ S, const float* __restrict__ u,
    float* __restrict__ pm, float* __restrict__ ps)
{
    int j = blockIdx.x * 256 + threadIdx.x;
    int b = blockIdx.z;
    int i0 = blockIdx.y * 128;
    int i1 = min(i0 + 128, MP1);
    if (j >= NP1) return;
    const float* p  = S + ((size_t)b * MP1 + i0) * NP1 + j;
    const float* ub = u + b * MP1;
    float sm = 0.f;
    for (int i = i0; i < i1; ++i) {
        sm += expf(*p + ub[i]);
        p += NP1;
    }
    int idx = (blockIdx.y * B_ + b) * NP1 + j;
    pm[idx] = 0.f;
    ps[idx] = sm;
}

__global__ __launch_bounds__(256) void col_pass2_kernel(
    const float* __restrict__ pm, const float* __restrict__ ps, float* __restrict__ v)
{
    int j = blockIdx.x * 256 + threadIdx.x;
    int b = blockIdx.y;
    if (j >= NP1) return;
    float Ssum = 0.f;
    #pragma unroll
    for (int c = 0; c < 9; ++c) Ssum += ps[(c * B_ + b) * NP1 + j];
    float lb = (j == N_) ? LOG_HALF : LOG_NORM;
    v[b * NP1 + j] = lb - logf(Ssum);
}

__global__ __launch_bounds__(256) void row_final_kernel(
    float* __restrict__ S, const float* __restrict__ v)
{
    int w = (blockIdx.x * 256 + threadIdx.x) >> 6;
    int lane = threadIdx.x & 63;
    if (w >= B_ * MP1) return;
    int b = w / MP1, i = w % MP1;
    float* row = S + ((size_t)b * MP1 + i) * NP1;
    const float* vb = v + b * NP1;
    float et[17];
    float sm = 0.f;
    #pragma unroll
    for (int q = 0; q < 17; ++q) {
        int j = lane + q * 64;
        float e = 0.f;
        if (j < NP1) e = expf(row[j] + vb[j]);
        et[q] = e;
        sm += e;
    }
    #pragma unroll
    for (int o = 32; o; o >>= 1) sm += __shfl_xor(sm, o);
    float A = (i == M_) ? 0.5f : (1.0f / 2048.0f);
    float scale = (A / sm) * 2048.0f;
    #pragma unroll
    for (int q = 0; q < 17; ++q) {
        int j = lane + q * 64;
        if (j < NP1) row[j] = et[q] * scale;
    }
}

__global__ __launch_bounds__(256) void zero_kernel(float* __restrict__ p, int n)
{
    int i = blockIdx.x * 256 + threadIdx.x;
    if (i < n) p[i] = 0.f;
}

extern "C" void kernel_launch(void* const* d_in, const int* in_sizes, int n_in,
                              void* d_out, int out_size, void* d_ws, size_t ws_size,
                              hipStream_t stream)
{
    const float* tf    = (const float*)d_in[0];
    const float* df    = (const float*)d_in[1];
    const float* tl    = (const float*)d_in[2];
    const float* dl    = (const float*)d_in[3];
    const float* alpha = (const float*)d_in[4];
    const float* eps   = (const float*)d_in[5];
    float* out = (float*)d_out;

    const size_t bf_one    = (size_t)B_ * M_ * D_ * 2;            // one bf16 feature matrix
    const size_t sh_bytes  = (size_t)B_ * MP1 * SH_STRIDE * 2;    // fp16 S
    const size_t small_f   = (size_t)B_ * M_ * 2 + (size_t)B_ * VSTR;  // inv1,inv2,v floats
    const size_t need_pre  = 2 * bf_one + sh_bytes + small_f * 4 + 512;
    const size_t need_mid  = sh_bytes + small_f * 4 + 512;

    int rowblocks = (B_ * MP1 + 3) / 4;
    int initblocks = (B_ * VSTR + B_ * (NP1 + M_) + 255) / 256;

    if (ws_size >= need_pre) {
        unsigned short* tfh = (unsigned short*)d_ws;
        unsigned short* dfh = tfh + (size_t)B_ * M_ * D_;
        _Float16* Sh = (_Float16*)((char*)d_ws + 2 * bf_one);
        float* fbase = (float*)((char*)d_ws + ((2 * bf_one + sh_bytes + 255) & ~(size_t)255));
        float* inv1 = fbase;
        float* inv2 = inv1 + B_ * M_;
        float* v    = inv2 + B_ * N_;
        float* ps   = out;

        init_h_kernel<<<initblocks, 256, 0, stream>>>(v, Sh, alpha, eps);
        norms_kernel_t<true><<<(B_ * 2048) / 4, 256, 0, stream>>>(tf, df, inv1, inv2, tfh, dfh);
        gemm_s_kernel<2><<<1024, 256, 0, stream>>>(tfh, dfh, tl, dl, inv1, inv2, eps, Sh);

        for (int it = 0; it < NUM_SINK; ++it) {
            fused_rowcol_h<<<dim3(NCH, B_), 256, 0, stream>>>(Sh, v, ps);
            col_pass2_f<<<dim3(5, B_), 256, 0, stream>>>(ps, v);
        }
        row_final_h<<<rowblocks, 256, 0, stream>>>(Sh, v, out);
    } else if (ws_size >= need_mid) {
        _Float16* Sh = (_Float16*)d_ws;
        float* fbase = (float*)((char*)d_ws + ((sh_bytes + 255) & ~(size_t)255));
        float* inv1 = fbase;
        float* inv2 = inv1 + B_ * M_;
        float* v    = inv2 + B_ * N_;
        float* ps   = out;

        init_h_kernel<<<initblocks, 256, 0, stream>>>(v, Sh, alpha, eps);
        norms_kernel_t<false><<<(B_ * 2048) / 4, 256, 0, stream>>>(tf, df, inv1, inv2, nullptr, nullptr);
        gemm_s_kernel<1><<<1024, 256, 0, stream>>>(tf, df, tl, dl, inv1, inv2, eps, Sh);

        for (int it = 0; it < NUM_SINK; ++it) {
            fused_rowcol_h<<<dim3(NCH, B_), 256, 0, stream>>>(Sh, v, ps);
            col_pass2_f<<<dim3(5, B_), 256, 0, stream>>>(ps, v);
        }
        row_final_h<<<rowblocks, 256, 0, stream>>>(Sh, v, out);
    } else {
        float* S = out;
        float* ws = (float*)d_ws;
        float* inv1 = ws;
        float* inv2 = inv1 + B_ * M_;
        float* u    = inv2 + B_ * N_;
        float* v    = u + B_ * MP1;
        float* pm   = v + B_ * NP1;
        float* ps   = pm + 9 * B_ * NP1;

        zero_kernel<<<(B_ * NP1 + 255) / 256, 256, 0, stream>>>(v, B_ * NP1);
        norms_kernel_t<false><<<(B_ * 2048) / 4, 256, 0, stream>>>(tf, df, inv1, inv2, nullptr, nullptr);
        gemm_s_kernel<0><<<1024, 256, 0, stream>>>(tf, df, tl, dl, inv1, inv2, eps, S);
        fill_edges_f32<<<(B_ * (NP1 + M_) + 255) / 256, 256, 0, stream>>>(S, alpha, eps);

        for (int it = 0; it < NUM_SINK; ++it) {
            row_pass_kernel<<<rowblocks, 256, 0, stream>>>(S, v, u);
            col_pass1_kernel<<<dim3(5, 9, 16), 256, 0, stream>>>(S, u, pm, ps);
            col_pass2_kernel<<<dim3(5, 16), 256, 0, stream>>>(pm, ps, v);
        }
        row_final_kernel<<<rowblocks, 256, 0, stream>>>(S, v);
    }
}

// Round 8
// 168.727 us; speedup vs baseline: 2.1361x; 1.3163x over previous
//
#include <hip/hip_runtime.h>
#include <math.h>

#define B_ 16
#define M_ 1024
#define N_ 1024
#define D_ 512
#define MP1 1025
#define NP1 1025
#define NUM_SINK 8
#define BK 64
#define SSTR 1024        // fp16 S row stride (elements) — interior only, no edges
#define VSTR 1028        // v stride (floats), 16B-aligned
// log(1/2048), log(1/2)
#define LOG_NORM (-7.6246189861593985f)
#define LOG_HALF (-0.6931471805599453f)

typedef __attribute__((ext_vector_type(8))) short bf16x8;
typedef __attribute__((ext_vector_type(4))) float f32x4;
typedef __attribute__((ext_vector_type(8))) _Float16 h16x8;

__device__ inline short f2bf(float x) {
    unsigned u = __builtin_bit_cast(unsigned, x);
    u = (u + 0x7FFFu + ((u >> 16) & 1u)) >> 16;
    return (short)u;
}

__device__ inline void gload16(const void* g, void* l) {
    __builtin_amdgcn_global_load_lds(
        (const __attribute__((address_space(1))) unsigned int*)g,
        (__attribute__((address_space(3))) unsigned int*)l, 16, 0, 0);
}

// ---------------- norms: one wave per feature row ----------------
// PRE=true : write PRESCALED bf16 features (a/|a|), no inv output.
// PRE=false: write inv norms only (tier2/3).
template<bool PRE>
__global__ __launch_bounds__(256) void norms_kernel_t(
    const float* __restrict__ tf, const float* __restrict__ df,
    float* __restrict__ inv1, float* __restrict__ inv2,
    unsigned short* __restrict__ tfh, unsigned short* __restrict__ dfh)
{
    int w = (blockIdx.x * 256 + threadIdx.x) >> 6;
    int lane = threadIdx.x & 63;
    if (w >= B_ * 2048) return;
    int b = w >> 11;
    int rr = w & 2047;
    const float* src;
    float* dst = nullptr;
    unsigned short* dsth = nullptr;
    if (rr < M_) { src = tf + ((size_t)b * M_ + rr) * D_;
                   if (!PRE) dst = inv1 + b * M_ + rr;
                   if (PRE)  dsth = tfh + ((size_t)b * M_ + rr) * D_; }
    else         { src = df + ((size_t)b * N_ + (rr - M_)) * D_;
                   if (!PRE) dst = inv2 + b * N_ + (rr - M_);
                   if (PRE)  dsth = dfh + ((size_t)b * N_ + (rr - M_)) * D_; }
    float4 x = *(const float4*)(src + lane * 4);
    float4 y = *(const float4*)(src + 256 + lane * 4);
    float ss = x.x*x.x + x.y*x.y + x.z*x.z + x.w*x.w
             + y.x*y.x + y.y*y.y + y.z*y.z + y.w*y.w;
    #pragma unroll
    for (int o = 32; o; o >>= 1) ss += __shfl_xor(ss, o);
    if (PRE) {
        float rn = rsqrtf(ss);
        ushort4 hx, hy;
        hx.x = (unsigned short)f2bf(x.x*rn); hx.y = (unsigned short)f2bf(x.y*rn);
        hx.z = (unsigned short)f2bf(x.z*rn); hx.w = (unsigned short)f2bf(x.w*rn);
        hy.x = (unsigned short)f2bf(y.x*rn); hy.y = (unsigned short)f2bf(y.y*rn);
        hy.z = (unsigned short)f2bf(y.z*rn); hy.w = (unsigned short)f2bf(y.w*rn);
        *(ushort4*)(dsth + lane * 4) = hx;
        *(ushort4*)(dsth + 256 + lane * 4) = hy;
    } else {
        if (lane == 0) *dst = 1.0f / sqrtf(ss);
    }
}

// ---------------- MFMA GEMM + epilogue: S = (cos*mask - 1)/lambda ----------------
// MODE 0: fp32 out (NP1 stride), f2bf staging, inv in epilogue.
// MODE 1: fp16 out (SSTR), f2bf staging, inv in epilogue.
// MODE 2: fp16 out (SSTR), global_load_lds from PRESCALED bf16 (no inv).
template<int MODE>
__global__ __launch_bounds__(256) void gemm_s_kernel(
    const void* __restrict__ A, const void* __restrict__ Bm,
    const float* __restrict__ tl, const float* __restrict__ dl,
    const float* __restrict__ inv1, const float* __restrict__ inv2,
    const float* __restrict__ eps_p, void* __restrict__ Sout)
{
    __shared__ __align__(16) unsigned short As[128 * BK];
    __shared__ __align__(16) unsigned short Bs[128 * BK];

    int flat = blockIdx.x;
    int swz = (flat & 7) * 128 + (flat >> 3);
    int jb = swz & 7, ib = (swz >> 3) & 7;
    int b  = swz >> 6;
    int i0 = ib * 128;
    int j0 = jb * 128;

    int tid  = threadIdx.x;
    int lane = tid & 63;
    int w    = tid >> 6;
    int wm   = w >> 1, wn = w & 1;

    f32x4 acc[4][4] = {};

    if constexpr (MODE == 2) {
        const unsigned short* Ah = (const unsigned short*)A  + (size_t)b * M_ * D_;
        const unsigned short* Bh = (const unsigned short*)Bm + (size_t)b * N_ * D_;
        int gcol = ((lane & 7) ^ (lane >> 3)) << 3;
        int rloc = lane >> 3;
        for (int k0 = 0; k0 < D_; k0 += BK) {
            #pragma unroll
            for (int c = 0; c < 4; ++c) {
                int r = (w * 4 + c) * 8 + rloc;
                gload16(Ah + (size_t)(i0 + r) * D_ + k0 + gcol,
                        (char*)As + (w * 4 + c) * 1024 + lane * 16);
                gload16(Bh + (size_t)(j0 + r) * D_ + k0 + gcol,
                        (char*)Bs + (w * 4 + c) * 1024 + lane * 16);
            }
            __syncthreads();
            #pragma unroll
            for (int ks = 0; ks < 2; ++ks) {
                int kb = ks * 64 + ((lane >> 4) << 4);
                bf16x8 af[4], bfr[4];
                #pragma unroll
                for (int m = 0; m < 4; ++m) {
                    int ra = wm * 64 + m * 16 + (lane & 15);
                    af[m] = *(const bf16x8*)((const char*)As + ra * 128 + (kb ^ ((ra & 7) << 4)));
                    int rb = wn * 64 + m * 16 + (lane & 15);
                    bfr[m] = *(const bf16x8*)((const char*)Bs + rb * 128 + (kb ^ ((rb & 7) << 4)));
                }
                #pragma unroll
                for (int m = 0; m < 4; ++m)
                    #pragma unroll
                    for (int n = 0; n < 4; ++n)
                        acc[m][n] = __builtin_amdgcn_mfma_f32_16x16x32_bf16(af[m], bfr[n], acc[m][n], 0, 0, 0);
            }
            __syncthreads();
        }
    } else {
        const float* Ab = (const float*)A  + (size_t)b * M_ * D_;
        const float* Bb = (const float*)Bm + (size_t)b * N_ * D_;
        int seg   = tid & 7;
        int rbase = tid >> 3;
        for (int k0 = 0; k0 < D_; k0 += BK) {
            #pragma unroll
            for (int rr = 0; rr < 4; ++rr) {
                int r = rbase + rr * 32;
                int colx = (seg * 16) ^ ((r & 7) << 4);
                {
                    const float* pa = Ab + (size_t)(i0 + r) * D_ + k0 + seg * 8;
                    float4 a0 = *(const float4*)pa;
                    float4 a1 = *(const float4*)(pa + 4);
                    bf16x8 hv;
                    hv[0] = f2bf(a0.x); hv[1] = f2bf(a0.y); hv[2] = f2bf(a0.z); hv[3] = f2bf(a0.w);
                    hv[4] = f2bf(a1.x); hv[5] = f2bf(a1.y); hv[6] = f2bf(a1.z); hv[7] = f2bf(a1.w);
                    *(bf16x8*)((char*)As + r * 128 + colx) = hv;
                }
                {
                    const float* pb = Bb + (size_t)(j0 + r) * D_ + k0 + seg * 8;
                    float4 b0 = *(const float4*)pb;
                    float4 b1 = *(const float4*)(pb + 4);
                    bf16x8 hv;
                    hv[0] = f2bf(b0.x); hv[1] = f2bf(b0.y); hv[2] = f2bf(b0.z); hv[3] = f2bf(b0.w);
                    hv[4] = f2bf(b1.x); hv[5] = f2bf(b1.y); hv[6] = f2bf(b1.z); hv[7] = f2bf(b1.w);
                    *(bf16x8*)((char*)Bs + r * 128 + colx) = hv;
                }
            }
            __syncthreads();
            #pragma unroll
            for (int ks = 0; ks < 2; ++ks) {
                int kb = ks * 64 + ((lane >> 4) << 4);
                bf16x8 af[4], bfr[4];
                #pragma unroll
                for (int m = 0; m < 4; ++m) {
                    int ra = wm * 64 + m * 16 + (lane & 15);
                    af[m] = *(const bf16x8*)((const char*)As + ra * 128 + (kb ^ ((ra & 7) << 4)));
                    int rb = wn * 64 + m * 16 + (lane & 15);
                    bfr[m] = *(const bf16x8*)((const char*)Bs + rb * 128 + (kb ^ ((rb & 7) << 4)));
                }
                #pragma unroll
                for (int m = 0; m < 4; ++m)
                    #pragma unroll
                    for (int n = 0; n < 4; ++n)
                        acc[m][n] = __builtin_amdgcn_mfma_f32_16x16x32_bf16(af[m], bfr[n], acc[m][n], 0, 0, 0);
            }
            __syncthreads();
        }
    }

    float lam = __expf(eps_p[0]) + 0.03f;
    float inv_lam = 1.0f / lam;
    int crow0 = i0 + wm * 64;
    int ccol0 = j0 + wn * 64;
    int rlane = lane >> 4;
    int clane = lane & 15;

    float invb_[4], dlx_[4], dly_[4];
    #pragma unroll
    for (int n = 0; n < 4; ++n) {
        int j = ccol0 + n * 16 + clane;
        if (MODE != 2) invb_[n] = inv2[b * N_ + j];
        dlx_[n]  = dl[((size_t)b * N_ + j) * 2 + 0];
        dly_[n]  = dl[((size_t)b * N_ + j) * 2 + 1];
    }
    #pragma unroll
    for (int m = 0; m < 4; ++m) {
        #pragma unroll
        for (int reg = 0; reg < 4; ++reg) {
            int i = crow0 + m * 16 + rlane * 4 + reg;
            float inva = (MODE != 2) ? inv1[b * M_ + i] : 1.0f;
            float tlx  = tl[((size_t)b * M_ + i) * 2 + 0];
            float tly  = tl[((size_t)b * M_ + i) * 2 + 1];
            #pragma unroll
            for (int n = 0; n < 4; ++n) {
                float cosv = (MODE == 2) ? acc[m][n][reg]
                                         : acc[m][n][reg] * inva * invb_[n];
                float dx = tlx - dlx_[n];
                float dy = tly - dly_[n];
                float msk = (dx * dx + dy * dy <= 0.09f) ? 1.0f : 0.0f;
                float val = (cosv * msk - 1.0f) * inv_lam;
                int col = ccol0 + n * 16 + clane;
                if (MODE >= 1) {
                    _Float16* Srow = (_Float16*)Sout + ((size_t)b * M_ + i) * SSTR;
                    Srow[col] = (_Float16)val;
                } else {
                    float* Srow = (float*)Sout + ((size_t)b * MP1 + i) * NP1;
                    Srow[col] = val;
                }
            }
        }
    }
}

// ---------------- init: zero v + init sums_p ping-pong ----------------
__global__ __launch_bounds__(256) void init_hv(
    float* __restrict__ v, float* __restrict__ sums_p)
{
    int t = blockIdx.x * 256 + threadIdx.x;
    if (t < B_ * VSTR) v[t] = 0.f;
    int u2 = t - B_ * VSTR;
    if (u2 >= 0 && u2 < 2 * B_ * 17) {
        int p = u2 / (B_ * 17), s = u2 % 17;
        sums_p[u2] = (p == 0 && s == 0) ? 1025.0f : 0.f;   // sum exp(v=0) over 1025
    }
}

// ================= fp16 path: fused row-update + column partials =================
// 32 rows/block (4 waves x 8 rows). No dustbin reads: col-1024 term is the
// constant et16c = exp(s_a + v[1024]); dustbin row handled analytically.
__global__ __launch_bounds__(256) void rowcol32(
    const _Float16* __restrict__ Sh, const float* __restrict__ v,
    float* __restrict__ ps,
    const float* __restrict__ alpha_p, const float* __restrict__ eps_p)
{
    int blk = blockIdx.x;           // 0..511
    int b = blk >> 5, k = blk & 31;
    int tid = threadIdx.x, lane = tid & 63, w = tid >> 6;

    __shared__ float red[4][64][17];   // stride-17 words: conflict-free

    const float* vb = v + (size_t)b * VSTR;
    float vreg[16];
    {
        float4 v0 = *(const float4*)(vb + lane * 8);
        float4 v1 = *(const float4*)(vb + lane * 8 + 4);
        float4 v2 = *(const float4*)(vb + 512 + lane * 8);
        float4 v3 = *(const float4*)(vb + 512 + lane * 8 + 4);
        vreg[0]=v0.x; vreg[1]=v0.y; vreg[2]=v0.z; vreg[3]=v0.w;
        vreg[4]=v1.x; vreg[5]=v1.y; vreg[6]=v1.z; vreg[7]=v1.w;
        vreg[8]=v2.x; vreg[9]=v2.y; vreg[10]=v2.z; vreg[11]=v2.w;
        vreg[12]=v3.x; vreg[13]=v3.y; vreg[14]=v3.z; vreg[15]=v3.w;
    }
    float lam = __expf(eps_p[0]) + 0.03f;
    float s_a = (alpha_p[0] - 1.0f) / lam;
    float et16c = __expf(s_a + vb[1024]);

    const _Float16* Sb = Sh + ((size_t)b << 20);
    int rbase = k * 32 + w * 8;

    float creg[16] = {};
    float sum_scale = 0.f;

    #pragma unroll
    for (int g = 0; g < 2; ++g) {
        h16x8 h0[4], h1[4];
        #pragma unroll
        for (int rr = 0; rr < 4; ++rr) {
            const _Float16* row = Sb + (size_t)(rbase + g * 4 + rr) * SSTR;
            h0[rr] = *(const h16x8*)(row + lane * 8);
            h1[rr] = *(const h16x8*)(row + 512 + lane * 8);
        }
        #pragma unroll
        for (int rr = 0; rr < 4; ++rr) {
            float et[16];
            float rs = 0.f;
            #pragma unroll
            for (int e = 0; e < 8; ++e) { et[e] = __expf((float)h0[rr][e] + vreg[e]); rs += et[e]; }
            #pragma unroll
            for (int e = 0; e < 8; ++e) { et[8+e] = __expf((float)h1[rr][e] + vreg[8+e]); rs += et[8+e]; }
            #pragma unroll
            for (int o = 32; o; o >>= 1) rs += __shfl_xor(rs, o);
            rs += et16c;                                   // dustbin column term
            float scale = (1.0f / 2048.0f) / rs;           // exp(u_i)
            #pragma unroll
            for (int e = 0; e < 16; ++e) creg[e] += et[e] * scale;
            sum_scale += scale;
        }
    }

    #pragma unroll
    for (int e = 0; e < 16; ++e) red[w][lane][e] = creg[e];
    if (lane == 0) red[w][0][16] = sum_scale;
    __syncthreads();

    float* pso = ps + (size_t)(k * 16 + b) * 1025;
    for (int j = tid; j < 1024; j += 256) {
        int lane_j = (j & 511) >> 3;
        int e_j    = ((j >> 9) << 3) | (j & 7);
        pso[j] = red[0][lane_j][e_j] + red[1][lane_j][e_j]
               + red[2][lane_j][e_j] + red[3][lane_j][e_j];
    }
    if (tid == 0)
        pso[1024] = et16c * (red[0][0][16] + red[1][0][16] + red[2][0][16] + red[3][0][16]);
}

// col update: one wave per (b, 64-col segment). 272 waves = 68 blocks.
// colsum_j = sum_k ps[k][b][j] + 0.5*exp(v_j)/sum_old  (dustbin row, analytic)
// v_new = v_old + lb - log(colsum); per-wave partial of sum exp(v_new) -> sums_p
__global__ __launch_bounds__(256) void colpass32(
    const float* __restrict__ ps, float* __restrict__ v,
    float* __restrict__ sums_p, int it)
{
    int gw = blockIdx.x * 4 + (threadIdx.x >> 6);
    int lane = threadIdx.x & 63;
    if (gw >= B_ * 17) return;
    int b = gw / 17, seg = gw % 17;
    int j = seg * 64 + lane;
    int par = it & 1;
    float sum_old = 0.f;
    #pragma unroll
    for (int s = 0; s < 17; ++s) sum_old += sums_p[par * (B_ * 17) + b * 17 + s];
    float ev = 0.f;
    if (j <= 1024) {
        size_t vidx = (size_t)b * VSTR + j;
        float vj = v[vidx];
        const float* pp = ps + (size_t)b * 1025 + j;
        float cs = 0.f;
        #pragma unroll 8
        for (int c = 0; c < 32; ++c) cs += pp[(size_t)c * (16 * 1025)];
        cs += 0.5f * __expf(vj) / sum_old;
        float lb = (j == 1024) ? LOG_HALF : LOG_NORM;
        float vn = vj + lb - __logf(cs);
        v[vidx] = vn;
        ev = __expf(vn);
    }
    #pragma unroll
    for (int o = 32; o; o >>= 1) ev += __shfl_xor(ev, o);
    if (lane == 0) sums_p[(par ^ 1) * (B_ * 17) + b * 17 + seg] = ev;
}

// final: blocks <512 write interior rows (+dustbin col); blocks >=512 write dustbin row
__global__ __launch_bounds__(256) void final32(
    const _Float16* __restrict__ Sh, const float* __restrict__ v,
    const float* __restrict__ sums_p,
    const float* __restrict__ alpha_p, const float* __restrict__ eps_p,
    float* __restrict__ out)
{
    int blk = blockIdx.x;
    int tid = threadIdx.x, lane = tid & 63, w = tid >> 6;

    if (blk >= 512) {
        int gw = (blk - 512) * 4 + w;
        if (gw >= B_ * 17) return;
        int b = gw / 17, seg = gw % 17, j = seg * 64 + lane;
        if (j > 1024) return;
        float sumv = 0.f;
        int par = NUM_SINK & 1;
        #pragma unroll
        for (int s = 0; s < 17; ++s) sumv += sums_p[par * (B_ * 17) + b * 17 + s];
        out[((size_t)b * MP1 + 1024) * NP1 + j] = __expf(v[(size_t)b * VSTR + j]) * 1024.0f / sumv;
        return;
    }

    int b = blk >> 5, k = blk & 31;
    const float* vb = v + (size_t)b * VSTR;
    float vreg[16];
    {
        float4 v0 = *(const float4*)(vb + lane * 8);
        float4 v1 = *(const float4*)(vb + lane * 8 + 4);
        float4 v2 = *(const float4*)(vb + 512 + lane * 8);
        float4 v3 = *(const float4*)(vb + 512 + lane * 8 + 4);
        vreg[0]=v0.x; vreg[1]=v0.y; vreg[2]=v0.z; vreg[3]=v0.w;
        vreg[4]=v1.x; vreg[5]=v1.y; vreg[6]=v1.z; vreg[7]=v1.w;
        vreg[8]=v2.x; vreg[9]=v2.y; vreg[10]=v2.z; vreg[11]=v2.w;
        vreg[12]=v3.x; vreg[13]=v3.y; vreg[14]=v3.z; vreg[15]=v3.w;
    }
    float lam = __expf(eps_p[0]) + 0.03f;
    float s_a = (alpha_p[0] - 1.0f) / lam;
    float et16c = __expf(s_a + vb[1024]);

    const _Float16* Sb = Sh + ((size_t)b << 20);
    int rbase = k * 32 + w * 8;

    #pragma unroll
    for (int g = 0; g < 2; ++g) {
        h16x8 h0[4], h1[4];
        #pragma unroll
        for (int rr = 0; rr < 4; ++rr) {
            const _Float16* row = Sb + (size_t)(rbase + g * 4 + rr) * SSTR;
            h0[rr] = *(const h16x8*)(row + lane * 8);
            h1[rr] = *(const h16x8*)(row + 512 + lane * 8);
        }
        #pragma unroll
        for (int rr = 0; rr < 4; ++rr) {
            int r = rbase + g * 4 + rr;
            float et[16];
            float rs = 0.f;
            #pragma unroll
            for (int e = 0; e < 8; ++e) { et[e] = __expf((float)h0[rr][e] + vreg[e]); rs += et[e]; }
            #pragma unroll
            for (int e = 0; e < 8; ++e) { et[8+e] = __expf((float)h1[rr][e] + vreg[8+e]); rs += et[8+e]; }
            #pragma unroll
            for (int o = 32; o; o >>= 1) rs += __shfl_xor(rs, o);
            rs += et16c;
            float sc = 1.0f / rs;   // = exp(u)*2048
            float* orow = out + ((size_t)b * MP1 + r) * NP1;
            float4 o0 = {et[0]*sc,  et[1]*sc,  et[2]*sc,  et[3]*sc};
            float4 o1 = {et[4]*sc,  et[5]*sc,  et[6]*sc,  et[7]*sc};
            float4 o2 = {et[8]*sc,  et[9]*sc,  et[10]*sc, et[11]*sc};
            float4 o3 = {et[12]*sc, et[13]*sc, et[14]*sc, et[15]*sc};
            *(float4*)(orow + lane * 8)           = o0;
            *(float4*)(orow + lane * 8 + 4)       = o1;
            *(float4*)(orow + 512 + lane * 8)     = o2;
            *(float4*)(orow + 512 + lane * 8 + 4) = o3;
            if (lane == 0) orow[1024] = et16c * sc;
        }
    }
}

// ================= fp32 fallback kernels (tier 3, S in d_out) =================

__global__ __launch_bounds__(256) void fill_edges_f32(
    float* __restrict__ Sout, const float* __restrict__ alpha_p, const float* __restrict__ eps_p)
{
    int t = blockIdx.x * 256 + threadIdx.x;
    if (t >= B_ * (NP1 + M_)) return;
    int b = t / (NP1 + M_), r = t % (NP1 + M_);
    float lam = expf(eps_p[0]) + 0.03f;
    float s = (alpha_p[0] - 1.0f) / lam;
    size_t idx;
    if (r < NP1) idx = ((size_t)b * MP1 + M_) * NP1 + r;
    else         idx = ((size_t)b * MP1 + (r - NP1)) * NP1 + N_;
    Sout[idx] = s;
}

__global__ __launch_bounds__(256) void row_pass_kernel(
    const float* __restrict__ S, const float* __restrict__ v, float* __restrict__ u)
{
    int w = (blockIdx.x * 256 + threadIdx.x) >> 6;
    int lane = threadIdx.x & 63;
    if (w >= B_ * MP1) return;
    int b = w / MP1, i = w % MP1;
    const float* row = S + ((size_t)b * MP1 + i) * NP1;
    const float* vb = v + b * NP1;
    float sm = 0.f;
    #pragma unroll
    for (int q = 0; q < 17; ++q) {
        int j = lane + q * 64;
        if (j < NP1) sm += expf(row[j] + vb[j]);
    }
    #pragma unroll
    for (int o = 32; o; o >>= 1) sm += __shfl_xor(sm, o);
    if (lane == 0) {
        float la = (i == M_) ? LOG_HALF : LOG_NORM;
        u[b * MP1 + i] = la - logf(sm);
    }
}

__global__ __launch_bounds__(256) void col_pass1_kernel(
    const float* __restrict__ S, const float* __restrict__ u,
    float* __restrict__ pm, float* __restrict__ ps)
{
    int j = blockIdx.x * 256 + threadIdx.x;
    int b = blockIdx.z;
    int i0 = blockIdx.y * 128;
    int i1 = min(i0 + 128, MP1);
    if (j >= NP1) return;
    const float* p  = S + ((size_t)b * MP1 + i0) * NP1 + j;
    const float* ub = u + b * MP1;
    float sm = 0.f;
    for (int i = i0; i < i1; ++i) {
        sm += expf(*p + ub[i]);
        p += NP1;
    }
    int idx = (blockIdx.y * B_ + b) * NP1 + j;
    pm[idx] = 0.f;
    ps[idx] = sm;
}

__global__ __launch_bounds__(256) void col_pass2_kernel(
    const float* __restrict__ pm, const float* __restrict__ ps, float* __restrict__ v)
{
    int j = blockIdx.x * 256 + threadIdx.x;
    int b = blockIdx.y;
    if (j >= NP1) return;
    float Ssum = 0.f;
    #pragma unroll
    for (int c = 0; c < 9; ++c) Ssum += ps[(c * B_ + b) * NP1 + j];
    float lb = (j == N_) ? LOG_HALF : LOG_NORM;
    v[b * NP1 + j] = lb - logf(Ssum);
}

__global__ __launch_bounds__(256) void row_final_kernel(
    float* __restrict__ S, const float* __restrict__ v)
{
    int w = (blockIdx.x * 256 + threadIdx.x) >> 6;
    int lane = threadIdx.x & 63;
    if (w >= B_ * MP1) return;
    int b = w / MP1, i = w % MP1;
    float* row = S + ((size_t)b * MP1 + i) * NP1;
    const float* vb = v + b * NP1;
    float et[17];
    float sm = 0.f;
    #pragma unroll
    for (int q = 0; q < 17; ++q) {
        int j = lane + q * 64;
        float e = 0.f;
        if (j < NP1) e = expf(row[j] + vb[j]);
        et[q] = e;
        sm += e;
    }
    #pragma unroll
    for (int o = 32; o; o >>= 1) sm += __shfl_xor(sm, o);
    float A = (i == M_) ? 0.5f : (1.0f / 2048.0f);
    float scale = (A / sm) * 2048.0f;
    #pragma unroll
    for (int q = 0; q < 17; ++q) {
        int j = lane + q * 64;
        if (j < NP1) row[j] = et[q] * scale;
    }
}

__global__ __launch_bounds__(256) void zero_kernel(float* __restrict__ p, int n)
{
    int i = blockIdx.x * 256 + threadIdx.x;
    if (i < n) p[i] = 0.f;
}

extern "C" void kernel_launch(void* const* d_in, const int* in_sizes, int n_in,
                              void* d_out, int out_size, void* d_ws, size_t ws_size,
                              hipStream_t stream)
{
    const float* tf    = (const float*)d_in[0];
    const float* df    = (const float*)d_in[1];
    const float* tl    = (const float*)d_in[2];
    const float* dl    = (const float*)d_in[3];
    const float* alpha = (const float*)d_in[4];
    const float* eps   = (const float*)d_in[5];
    float* out = (float*)d_out;

    const size_t bf_one   = (size_t)B_ * M_ * D_ * 2;           // one bf16 feature matrix
    const size_t sh_bytes = (size_t)B_ * M_ * SSTR * 2;         // fp16 S (interior only)
    const size_t vf       = (size_t)B_ * VSTR;                  // v floats
    const size_t sums_f   = 2 * B_ * 17;                        // sums ping-pong floats
    const size_t invs_f   = (size_t)B_ * M_ * 2;                // inv1+inv2 floats (tier2)
    const size_t need_pre = 2 * bf_one + sh_bytes + (vf + sums_f) * 4 + 512;
    const size_t need_mid = sh_bytes + (vf + sums_f + invs_f) * 4 + 512;

    int initblocks = (int)((vf + sums_f + 255) / 256);

    if (ws_size >= need_pre) {
        unsigned short* tfh = (unsigned short*)d_ws;
        unsigned short* dfh = tfh + (size_t)B_ * M_ * D_;
        _Float16* Sh = (_Float16*)((char*)d_ws + 2 * bf_one);
        float* fbase = (float*)((char*)d_ws + ((2 * bf_one + sh_bytes + 255) & ~(size_t)255));
        float* v      = fbase;
        float* sums_p = v + vf;
        float* ps     = out;

        init_hv<<<initblocks, 256, 0, stream>>>(v, sums_p);
        norms_kernel_t<true><<<(B_ * 2048) / 4, 256, 0, stream>>>(tf, df, nullptr, nullptr, tfh, dfh);
        gemm_s_kernel<2><<<1024, 256, 0, stream>>>(tfh, dfh, tl, dl, nullptr, nullptr, eps, Sh);

        for (int it = 0; it < NUM_SINK; ++it) {
            rowcol32<<<512, 256, 0, stream>>>(Sh, v, ps, alpha, eps);
            colpass32<<<68, 256, 0, stream>>>(ps, v, sums_p, it);
        }
        final32<<<580, 256, 0, stream>>>(Sh, v, sums_p, alpha, eps, out);
    } else if (ws_size >= need_mid) {
        _Float16* Sh = (_Float16*)d_ws;
        float* fbase = (float*)((char*)d_ws + ((sh_bytes + 255) & ~(size_t)255));
        float* inv1   = fbase;
        float* inv2   = inv1 + B_ * M_;
        float* v      = inv2 + B_ * N_;
        float* sums_p = v + vf;
        float* ps     = out;

        init_hv<<<initblocks, 256, 0, stream>>>(v, sums_p);
        norms_kernel_t<false><<<(B_ * 2048) / 4, 256, 0, stream>>>(tf, df, inv1, inv2, nullptr, nullptr);
        gemm_s_kernel<1><<<1024, 256, 0, stream>>>(tf, df, tl, dl, inv1, inv2, eps, Sh);

        for (int it = 0; it < NUM_SINK; ++it) {
            rowcol32<<<512, 256, 0, stream>>>(Sh, v, ps, alpha, eps);
            colpass32<<<68, 256, 0, stream>>>(ps, v, sums_p, it);
        }
        final32<<<580, 256, 0, stream>>>(Sh, v, sums_p, alpha, eps, out);
    } else {
        float* S = out;
        float* ws = (float*)d_ws;
        float* inv1 = ws;
        float* inv2 = inv1 + B_ * M_;
        float* u    = inv2 + B_ * N_;
        float* v    = u + B_ * MP1;
        float* pm   = v + B_ * NP1;
        float* ps   = pm + 9 * B_ * NP1;

        zero_kernel<<<(B_ * NP1 + 255) / 256, 256, 0, stream>>>(v, B_ * NP1);
        norms_kernel_t<false><<<(B_ * 2048) / 4, 256, 0, stream>>>(tf, df, inv1, inv2, nullptr, nullptr);
        gemm_s_kernel<0><<<1024, 256, 0, stream>>>(tf, df, tl, dl, inv1, inv2, eps, S);
        fill_edges_f32<<<(B_ * (NP1 + M_) + 255) / 256, 256, 0, stream>>>(S, alpha, eps);

        int rowblocks = (B_ * MP1 + 3) / 4;
        for (int it = 0; it < NUM_SINK; ++it) {
            row_pass_kernel<<<rowblocks, 256, 0, stream>>>(S, v, u);
            col_pass1_kernel<<<dim3(5, 9, 16), 256, 0, stream>>>(S, u, pm, ps);
            col_pass2_kernel<<<dim3(5, 16), 256, 0, stream>>>(pm, ps, v);
        }
        row_final_kernel<<<rowblocks, 256, 0, stream>>>(S, v);
    }
}

// Round 9
// 161.802 us; speedup vs baseline: 2.2276x; 1.0428x over previous
//
#include <hip/hip_runtime.h>
#include <math.h>

#define B_ 16
#define M_ 1024
#define N_ 1024
#define D_ 512
#define MP1 1025
#define NP1 1025
#define NUM_SINK 8
#define BK 64
#define SSTR 1024        // fp16 S row stride (elements) — interior only, no edges
#define VSTR 1028        // v stride (floats), 16B-aligned
// log(1/2048), log(1/2)
#define LOG_NORM (-7.6246189861593985f)
#define LOG_HALF (-0.6931471805599453f)

typedef __attribute__((ext_vector_type(8))) short bf16x8;
typedef __attribute__((ext_vector_type(4))) float f32x4;
typedef __attribute__((ext_vector_type(8))) _Float16 h16x8;

__device__ inline short f2bf(float x) {
    unsigned u = __builtin_bit_cast(unsigned, x);
    u = (u + 0x7FFFu + ((u >> 16) & 1u)) >> 16;
    return (short)u;
}

__device__ inline void gload16(const void* g, void* l) {
    __builtin_amdgcn_global_load_lds(
        (const __attribute__((address_space(1))) unsigned int*)g,
        (__attribute__((address_space(3))) unsigned int*)l, 16, 0, 0);
}

// ---------------- norms (+init of v/sums in block 0): one wave per feature row ----------------
// PRE=true : write PRESCALED bf16 features (a/|a|); block 0 also inits v + sums_p.
// PRE=false: write inv norms only (tier2/3).
template<bool PRE>
__global__ __launch_bounds__(256) void norms_kernel_t(
    const float* __restrict__ tf, const float* __restrict__ df,
    float* __restrict__ inv1, float* __restrict__ inv2,
    unsigned short* __restrict__ tfh, unsigned short* __restrict__ dfh,
    float* __restrict__ v, float* __restrict__ sums_p)
{
    if (PRE && blockIdx.x == 0) {
        // init v = 0 and sums ping-pong (first combine sees sum exp(0)*1025)
        const int nv = B_ * VSTR, ns = 2 * B_ * 17;
        for (int t = threadIdx.x; t < nv + ns; t += 256) {
            if (t < nv) v[t] = 0.f;
            else {
                int u2 = t - nv;
                int p = u2 / (B_ * 17), s = u2 % 17;
                sums_p[u2] = (p == 0 && s == 0) ? 1025.0f : 0.f;
            }
        }
    }
    int w = (blockIdx.x * 256 + threadIdx.x) >> 6;
    int lane = threadIdx.x & 63;
    if (w >= B_ * 2048) return;
    int b = w >> 11;
    int rr = w & 2047;
    const float* src;
    float* dst = nullptr;
    unsigned short* dsth = nullptr;
    if (rr < M_) { src = tf + ((size_t)b * M_ + rr) * D_;
                   if (!PRE) dst = inv1 + b * M_ + rr;
                   if (PRE)  dsth = tfh + ((size_t)b * M_ + rr) * D_; }
    else         { src = df + ((size_t)b * N_ + (rr - M_)) * D_;
                   if (!PRE) dst = inv2 + b * N_ + (rr - M_);
                   if (PRE)  dsth = dfh + ((size_t)b * N_ + (rr - M_)) * D_; }
    float4 x = *(const float4*)(src + lane * 4);
    float4 y = *(const float4*)(src + 256 + lane * 4);
    float ss = x.x*x.x + x.y*x.y + x.z*x.z + x.w*x.w
             + y.x*y.x + y.y*y.y + y.z*y.z + y.w*y.w;
    #pragma unroll
    for (int o = 32; o; o >>= 1) ss += __shfl_xor(ss, o);
    if (PRE) {
        float rn = rsqrtf(ss);
        ushort4 hx, hy;
        hx.x = (unsigned short)f2bf(x.x*rn); hx.y = (unsigned short)f2bf(x.y*rn);
        hx.z = (unsigned short)f2bf(x.z*rn); hx.w = (unsigned short)f2bf(x.w*rn);
        hy.x = (unsigned short)f2bf(y.x*rn); hy.y = (unsigned short)f2bf(y.y*rn);
        hy.z = (unsigned short)f2bf(y.z*rn); hy.w = (unsigned short)f2bf(y.w*rn);
        *(ushort4*)(dsth + lane * 4) = hx;
        *(ushort4*)(dsth + 256 + lane * 4) = hy;
    } else {
        if (lane == 0) *dst = 1.0f / sqrtf(ss);
    }
}

// ---------------- MFMA GEMM + epilogue: S = (cos*mask - 1)/lambda ----------------
// MODE 0: fp32 out (NP1 stride), f2bf staging, inv in epilogue.
// MODE 1: fp16 out (SSTR), f2bf staging, inv in epilogue.
// MODE 2: fp16 out (SSTR), global_load_lds from PRESCALED bf16, DOUBLE-BUFFERED (T3 2-phase).
template<int MODE>
__global__ __launch_bounds__(256) void gemm_s_kernel(
    const void* __restrict__ A, const void* __restrict__ Bm,
    const float* __restrict__ tl, const float* __restrict__ dl,
    const float* __restrict__ inv1, const float* __restrict__ inv2,
    const float* __restrict__ eps_p, void* __restrict__ Sout)
{
    __shared__ __align__(16) unsigned short As[2][128 * BK];   // 2 x 16 KB
    __shared__ __align__(16) unsigned short Bs[2][128 * BK];   // 2 x 16 KB

    int flat = blockIdx.x;
    int swz = (flat & 7) * 128 + (flat >> 3);
    int jb = swz & 7, ib = (swz >> 3) & 7;
    int b  = swz >> 6;
    int i0 = ib * 128;
    int j0 = jb * 128;

    int tid  = threadIdx.x;
    int lane = tid & 63;
    int w    = tid >> 6;
    int wm   = w >> 1, wn = w & 1;

    f32x4 acc[4][4] = {};

    if constexpr (MODE == 2) {
        const unsigned short* Ah = (const unsigned short*)A  + (size_t)b * M_ * D_;
        const unsigned short* Bh = (const unsigned short*)Bm + (size_t)b * N_ * D_;
        int gcol = ((lane & 7) ^ (lane >> 3)) << 3;   // pre-swizzled source element offset
        int rloc = lane >> 3;

        auto stage = [&](int k0, int buf) {
            #pragma unroll
            for (int c = 0; c < 4; ++c) {
                int r = (w * 4 + c) * 8 + rloc;
                gload16(Ah + (size_t)(i0 + r) * D_ + k0 + gcol,
                        (char*)As[buf] + (w * 4 + c) * 1024 + lane * 16);
                gload16(Bh + (size_t)(j0 + r) * D_ + k0 + gcol,
                        (char*)Bs[buf] + (w * 4 + c) * 1024 + lane * 16);
            }
        };

        stage(0, 0);
        __syncthreads();
        int cur = 0;
        for (int t = 0; t < D_ / BK; ++t) {
            if (t < D_ / BK - 1) stage((t + 1) * BK, cur ^ 1);   // prefetch next tile
            #pragma unroll
            for (int ks = 0; ks < 2; ++ks) {
                int kb = ks * 64 + ((lane >> 4) << 4);
                bf16x8 af[4], bfr[4];
                #pragma unroll
                for (int m = 0; m < 4; ++m) {
                    int ra = wm * 64 + m * 16 + (lane & 15);
                    af[m] = *(const bf16x8*)((const char*)As[cur] + ra * 128 + (kb ^ ((ra & 7) << 4)));
                    int rb = wn * 64 + m * 16 + (lane & 15);
                    bfr[m] = *(const bf16x8*)((const char*)Bs[cur] + rb * 128 + (kb ^ ((rb & 7) << 4)));
                }
                #pragma unroll
                for (int m = 0; m < 4; ++m)
                    #pragma unroll
                    for (int n = 0; n < 4; ++n)
                        acc[m][n] = __builtin_amdgcn_mfma_f32_16x16x32_bf16(af[m], bfr[n], acc[m][n], 0, 0, 0);
            }
            __syncthreads();   // drains prefetch + guards buffer reuse
            cur ^= 1;
        }
    } else {
        const float* Ab = (const float*)A  + (size_t)b * M_ * D_;
        const float* Bb = (const float*)Bm + (size_t)b * N_ * D_;
        int seg   = tid & 7;
        int rbase = tid >> 3;
        for (int k0 = 0; k0 < D_; k0 += BK) {
            #pragma unroll
            for (int rr = 0; rr < 4; ++rr) {
                int r = rbase + rr * 32;
                int colx = (seg * 16) ^ ((r & 7) << 4);
                {
                    const float* pa = Ab + (size_t)(i0 + r) * D_ + k0 + seg * 8;
                    float4 a0 = *(const float4*)pa;
                    float4 a1 = *(const float4*)(pa + 4);
                    bf16x8 hv;
                    hv[0] = f2bf(a0.x); hv[1] = f2bf(a0.y); hv[2] = f2bf(a0.z); hv[3] = f2bf(a0.w);
                    hv[4] = f2bf(a1.x); hv[5] = f2bf(a1.y); hv[6] = f2bf(a1.z); hv[7] = f2bf(a1.w);
                    *(bf16x8*)((char*)As[0] + r * 128 + colx) = hv;
                }
                {
                    const float* pb = Bb + (size_t)(j0 + r) * D_ + k0 + seg * 8;
                    float4 b0 = *(const float4*)pb;
                    float4 b1 = *(const float4*)(pb + 4);
                    bf16x8 hv;
                    hv[0] = f2bf(b0.x); hv[1] = f2bf(b0.y); hv[2] = f2bf(b0.z); hv[3] = f2bf(b0.w);
                    hv[4] = f2bf(b1.x); hv[5] = f2bf(b1.y); hv[6] = f2bf(b1.z); hv[7] = f2bf(b1.w);
                    *(bf16x8*)((char*)Bs[0] + r * 128 + colx) = hv;
                }
            }
            __syncthreads();
            #pragma unroll
            for (int ks = 0; ks < 2; ++ks) {
                int kb = ks * 64 + ((lane >> 4) << 4);
                bf16x8 af[4], bfr[4];
                #pragma unroll
                for (int m = 0; m < 4; ++m) {
                    int ra = wm * 64 + m * 16 + (lane & 15);
                    af[m] = *(const bf16x8*)((const char*)As[0] + ra * 128 + (kb ^ ((ra & 7) << 4)));
                    int rb = wn * 64 + m * 16 + (lane & 15);
                    bfr[m] = *(const bf16x8*)((const char*)Bs[0] + rb * 128 + (kb ^ ((rb & 7) << 4)));
                }
                #pragma unroll
                for (int m = 0; m < 4; ++m)
                    #pragma unroll
                    for (int n = 0; n < 4; ++n)
                        acc[m][n] = __builtin_amdgcn_mfma_f32_16x16x32_bf16(af[m], bfr[n], acc[m][n], 0, 0, 0);
            }
            __syncthreads();
        }
    }

    float lam = __expf(eps_p[0]) + 0.03f;
    float inv_lam = 1.0f / lam;
    int crow0 = i0 + wm * 64;
    int ccol0 = j0 + wn * 64;
    int rlane = lane >> 4;
    int clane = lane & 15;

    float invb_[4], dlx_[4], dly_[4];
    #pragma unroll
    for (int n = 0; n < 4; ++n) {
        int j = ccol0 + n * 16 + clane;
        if (MODE != 2) invb_[n] = inv2[b * N_ + j];
        dlx_[n]  = dl[((size_t)b * N_ + j) * 2 + 0];
        dly_[n]  = dl[((size_t)b * N_ + j) * 2 + 1];
    }
    #pragma unroll
    for (int m = 0; m < 4; ++m) {
        #pragma unroll
        for (int reg = 0; reg < 4; ++reg) {
            int i = crow0 + m * 16 + rlane * 4 + reg;
            float inva = (MODE != 2) ? inv1[b * M_ + i] : 1.0f;
            float tlx  = tl[((size_t)b * M_ + i) * 2 + 0];
            float tly  = tl[((size_t)b * M_ + i) * 2 + 1];
            #pragma unroll
            for (int n = 0; n < 4; ++n) {
                float cosv = (MODE == 2) ? acc[m][n][reg]
                                         : acc[m][n][reg] * inva * invb_[n];
                float dx = tlx - dlx_[n];
                float dy = tly - dly_[n];
                float mi = (fmaf(dx, dx, dy * dy) <= 0.09f) ? inv_lam : 0.0f;
                float val = fmaf(cosv, mi, -inv_lam);   // (cos*mask - 1)/lambda
                int col = ccol0 + n * 16 + clane;
                if (MODE >= 1) {
                    _Float16* Srow = (_Float16*)Sout + ((size_t)b * M_ + i) * SSTR;
                    Srow[col] = (_Float16)val;
                } else {
                    float* Srow = (float*)Sout + ((size_t)b * MP1 + i) * NP1;
                    Srow[col] = val;
                }
            }
        }
    }
}

// ---------------- init (tier2): zero v + init sums_p ping-pong ----------------
__global__ __launch_bounds__(256) void init_hv(
    float* __restrict__ v, float* __restrict__ sums_p)
{
    int t = blockIdx.x * 256 + threadIdx.x;
    if (t < B_ * VSTR) v[t] = 0.f;
    int u2 = t - B_ * VSTR;
    if (u2 >= 0 && u2 < 2 * B_ * 17) {
        int p = u2 / (B_ * 17), s = u2 % 17;
        sums_p[u2] = (p == 0 && s == 0) ? 1025.0f : 0.f;
    }
}

// ================= fp16 path: fused row-update + column partials =================
// 32 rows/block (4 waves x 8 rows, all 8 preloaded). Dustbin handled analytically.
__global__ __launch_bounds__(256) void rowcol32(
    const _Float16* __restrict__ Sh, const float* __restrict__ v,
    float* __restrict__ ps,
    const float* __restrict__ alpha_p, const float* __restrict__ eps_p)
{
    int blk = blockIdx.x;           // 0..511
    int b = blk >> 5, k = blk & 31;
    int tid = threadIdx.x, lane = tid & 63, w = tid >> 6;

    __shared__ float red[4][64][17];   // stride-17 words: conflict-free

    const float* vb = v + (size_t)b * VSTR;
    float vreg[16];
    {
        float4 v0 = *(const float4*)(vb + lane * 8);
        float4 v1 = *(const float4*)(vb + lane * 8 + 4);
        float4 v2 = *(const float4*)(vb + 512 + lane * 8);
        float4 v3 = *(const float4*)(vb + 512 + lane * 8 + 4);
        vreg[0]=v0.x; vreg[1]=v0.y; vreg[2]=v0.z; vreg[3]=v0.w;
        vreg[4]=v1.x; vreg[5]=v1.y; vreg[6]=v1.z; vreg[7]=v1.w;
        vreg[8]=v2.x; vreg[9]=v2.y; vreg[10]=v2.z; vreg[11]=v2.w;
        vreg[12]=v3.x; vreg[13]=v3.y; vreg[14]=v3.z; vreg[15]=v3.w;
    }
    float lam = __expf(eps_p[0]) + 0.03f;
    float s_a = (alpha_p[0] - 1.0f) / lam;
    float et16c = __expf(s_a + vb[1024]);

    const _Float16* Sb = Sh + ((size_t)b << 20);
    int rbase = k * 32 + w * 8;

    // preload all 8 rows (16 independent 16B loads in flight)
    h16x8 h0[8], h1[8];
    #pragma unroll
    for (int rr = 0; rr < 8; ++rr) {
        const _Float16* row = Sb + (size_t)(rbase + rr) * SSTR;
        h0[rr] = *(const h16x8*)(row + lane * 8);
        h1[rr] = *(const h16x8*)(row + 512 + lane * 8);
    }

    float creg[16] = {};
    float sum_scale = 0.f;

    #pragma unroll
    for (int rr = 0; rr < 8; ++rr) {
        float et[16];
        float rs = 0.f;
        #pragma unroll
        for (int e = 0; e < 8; ++e) { et[e] = __expf((float)h0[rr][e] + vreg[e]); rs += et[e]; }
        #pragma unroll
        for (int e = 0; e < 8; ++e) { et[8+e] = __expf((float)h1[rr][e] + vreg[8+e]); rs += et[8+e]; }
        #pragma unroll
        for (int o = 32; o; o >>= 1) rs += __shfl_xor(rs, o);
        rs += et16c;                                   // dustbin column term
        float scale = (1.0f / 2048.0f) / rs;           // exp(u_i)
        #pragma unroll
        for (int e = 0; e < 16; ++e) creg[e] += et[e] * scale;
        sum_scale += scale;
    }

    #pragma unroll
    for (int e = 0; e < 16; ++e) red[w][lane][e] = creg[e];
    if (lane == 0) red[w][0][16] = sum_scale;
    __syncthreads();

    float* pso = ps + (size_t)(k * 16 + b) * 1025;
    for (int j = tid; j < 1024; j += 256) {
        int lane_j = (j & 511) >> 3;
        int e_j    = ((j >> 9) << 3) | (j & 7);
        pso[j] = red[0][lane_j][e_j] + red[1][lane_j][e_j]
               + red[2][lane_j][e_j] + red[3][lane_j][e_j];
    }
    if (tid == 0)
        pso[1024] = et16c * (red[0][0][16] + red[1][0][16] + red[2][0][16] + red[3][0][16]);
}

// col update: one wave per (b, 64-col segment). 272 waves = 68 blocks.
__global__ __launch_bounds__(256) void colpass32(
    const float* __restrict__ ps, float* __restrict__ v,
    float* __restrict__ sums_p, int it)
{
    int gw = blockIdx.x * 4 + (threadIdx.x >> 6);
    int lane = threadIdx.x & 63;
    if (gw >= B_ * 17) return;
    int b = gw / 17, seg = gw % 17;
    int j = seg * 64 + lane;
    int par = it & 1;
    float sum_old = 0.f;
    #pragma unroll
    for (int s = 0; s < 17; ++s) sum_old += sums_p[par * (B_ * 17) + b * 17 + s];
    float ev = 0.f;
    if (j <= 1024) {
        size_t vidx = (size_t)b * VSTR + j;
        float vj = v[vidx];
        const float* pp = ps + (size_t)b * 1025 + j;
        float cs = 0.f;
        #pragma unroll 8
        for (int c = 0; c < 32; ++c) cs += pp[(size_t)c * (16 * 1025)];
        cs += 0.5f * __expf(vj) / sum_old;
        float lb = (j == 1024) ? LOG_HALF : LOG_NORM;
        float vn = vj + lb - __logf(cs);
        v[vidx] = vn;
        ev = __expf(vn);
    }
    #pragma unroll
    for (int o = 32; o; o >>= 1) ev += __shfl_xor(ev, o);
    if (lane == 0) sums_p[(par ^ 1) * (B_ * 17) + b * 17 + seg] = ev;
}

// final: blocks <512 write interior rows (+dustbin col); blocks >=512 write dustbin row
__global__ __launch_bounds__(256) void final32(
    const _Float16* __restrict__ Sh, const float* __restrict__ v,
    const float* __restrict__ sums_p,
    const float* __restrict__ alpha_p, const float* __restrict__ eps_p,
    float* __restrict__ out)
{
    int blk = blockIdx.x;
    int tid = threadIdx.x, lane = tid & 63, w = tid >> 6;

    if (blk >= 512) {
        int gw = (blk - 512) * 4 + w;
        if (gw >= B_ * 17) return;
        int b = gw / 17, seg = gw % 17, j = seg * 64 + lane;
        if (j > 1024) return;
        float sumv = 0.f;
        int par = NUM_SINK & 1;
        #pragma unroll
        for (int s = 0; s < 17; ++s) sumv += sums_p[par * (B_ * 17) + b * 17 + s];
        out[((size_t)b * MP1 + 1024) * NP1 + j] = __expf(v[(size_t)b * VSTR + j]) * 1024.0f / sumv;
        return;
    }

    int b = blk >> 5, k = blk & 31;
    const float* vb = v + (size_t)b * VSTR;
    float vreg[16];
    {
        float4 v0 = *(const float4*)(vb + lane * 8);
        float4 v1 = *(const float4*)(vb + lane * 8 + 4);
        float4 v2 = *(const float4*)(vb + 512 + lane * 8);
        float4 v3 = *(const float4*)(vb + 512 + lane * 8 + 4);
        vreg[0]=v0.x; vreg[1]=v0.y; vreg[2]=v0.z; vreg[3]=v0.w;
        vreg[4]=v1.x; vreg[5]=v1.y; vreg[6]=v1.z; vreg[7]=v1.w;
        vreg[8]=v2.x; vreg[9]=v2.y; vreg[10]=v2.z; vreg[11]=v2.w;
        vreg[12]=v3.x; vreg[13]=v3.y; vreg[14]=v3.z; vreg[15]=v3.w;
    }
    float lam = __expf(eps_p[0]) + 0.03f;
    float s_a = (alpha_p[0] - 1.0f) / lam;
    float et16c = __expf(s_a + vb[1024]);

    const _Float16* Sb = Sh + ((size_t)b << 20);
    int rbase = k * 32 + w * 8;

    #pragma unroll
    for (int g = 0; g < 2; ++g) {
        h16x8 h0[4], h1[4];
        #pragma unroll
        for (int rr = 0; rr < 4; ++rr) {
            const _Float16* row = Sb + (size_t)(rbase + g * 4 + rr) * SSTR;
            h0[rr] = *(const h16x8*)(row + lane * 8);
            h1[rr] = *(const h16x8*)(row + 512 + lane * 8);
        }
        #pragma unroll
        for (int rr = 0; rr < 4; ++rr) {
            int r = rbase + g * 4 + rr;
            float et[16];
            float rs = 0.f;
            #pragma unroll
            for (int e = 0; e < 8; ++e) { et[e] = __expf((float)h0[rr][e] + vreg[e]); rs += et[e]; }
            #pragma unroll
            for (int e = 0; e < 8; ++e) { et[8+e] = __expf((float)h1[rr][e] + vreg[8+e]); rs += et[8+e]; }
            #pragma unroll
            for (int o = 32; o; o >>= 1) rs += __shfl_xor(rs, o);
            rs += et16c;
            float sc = 1.0f / rs;   // = exp(u)*2048
            float* orow = out + ((size_t)b * MP1 + r) * NP1;
            float4 o0 = {et[0]*sc,  et[1]*sc,  et[2]*sc,  et[3]*sc};
            float4 o1 = {et[4]*sc,  et[5]*sc,  et[6]*sc,  et[7]*sc};
            float4 o2 = {et[8]*sc,  et[9]*sc,  et[10]*sc, et[11]*sc};
            float4 o3 = {et[12]*sc, et[13]*sc, et[14]*sc, et[15]*sc};
            *(float4*)(orow + lane * 8)           = o0;
            *(float4*)(orow + lane * 8 + 4)       = o1;
            *(float4*)(orow + 512 + lane * 8)     = o2;
            *(float4*)(orow + 512 + lane * 8 + 4) = o3;
            if (lane == 0) orow[1024] = et16c * sc;
        }
    }
}

// ================= fp32 fallback kernels (tier 3, S in d_out) =================

__global__ __launch_bounds__(256) void fill_edges_f32(
    float* __restrict__ Sout, const float* __restrict__ alpha_p, const float* __restrict__ eps_p)
{
    int t = blockIdx.x * 256 + threadIdx.x;
    if (t >= B_ * (NP1 + M_)) return;
    int b = t / (NP1 + M_), r = t % (NP1 + M_);
    float lam = expf(eps_p[0]) + 0.03f;
    float s = (alpha_p[0] - 1.0f) / lam;
    size_t idx;
    if (r < NP1) idx = ((size_t)b * MP1 + M_) * NP1 + r;
    else         idx = ((size_t)b * MP1 + (r - NP1)) * NP1 + N_;
    Sout[idx] = s;
}

__global__ __launch_bounds__(256) void row_pass_kernel(
    const float* __restrict__ S, const float* __restrict__ v, float* __restrict__ u)
{
    int w = (blockIdx.x * 256 + threadIdx.x) >> 6;
    int lane = threadIdx.x & 63;
    if (w >= B_ * MP1) return;
    int b = w / MP1, i = w % MP1;
    const float* row = S + ((size_t)b * MP1 + i) * NP1;
    const float* vb = v + b * NP1;
    float sm = 0.f;
    #pragma unroll
    for (int q = 0; q < 17; ++q) {
        int j = lane + q * 64;
        if (j < NP1) sm += expf(row[j] + vb[j]);
    }
    #pragma unroll
    for (int o = 32; o; o >>= 1) sm += __shfl_xor(sm, o);
    if (lane == 0) {
        float la = (i == M_) ? LOG_HALF : LOG_NORM;
        u[b * MP1 + i] = la - logf(sm);
    }
}

__global__ __launch_bounds__(256) void col_pass1_kernel(
    const float* __restrict__ S, const float* __restrict__ u,
    float* __restrict__ pm, float* __restrict__ ps)
{
    int j = blockIdx.x * 256 + threadIdx.x;
    int b = blockIdx.z;
    int i0 = blockIdx.y * 128;
    int i1 = min(i0 + 128, MP1);
    if (j >= NP1) return;
    const float* p  = S + ((size_t)b * MP1 + i0) * NP1 + j;
    const float* ub = u + b * MP1;
    float sm = 0.f;
    for (int i = i0; i < i1; ++i) {
        sm += expf(*p + ub[i]);
        p += NP1;
    }
    int idx = (blockIdx.y * B_ + b) * NP1 + j;
    pm[idx] = 0.f;
    ps[idx] = sm;
}

__global__ __launch_bounds__(256) void col_pass2_kernel(
    const float* __restrict__ pm, const float* __restrict__ ps, float* __restrict__ v)
{
    int j = blockIdx.x * 256 + threadIdx.x;
    int b = blockIdx.y;
    if (j >= NP1) return;
    float Ssum = 0.f;
    #pragma unroll
    for (int c = 0; c < 9; ++c) Ssum += ps[(c * B_ + b) * NP1 + j];
    float lb = (j == N_) ? LOG_HALF : LOG_NORM;
    v[b * NP1 + j] = lb - logf(Ssum);
}

__global__ __launch_bounds__(256) void row_final_kernel(
    float* __restrict__ S, const float* __restrict__ v)
{
    int w = (blockIdx.x * 256 + threadIdx.x) >> 6;
    int lane = threadIdx.x & 63;
    if (w >= B_ * MP1) return;
    int b = w / MP1, i = w % MP1;
    float* row = S + ((size_t)b * MP1 + i) * NP1;
    const float* vb = v + b * NP1;
    float et[17];
    float sm = 0.f;
    #pragma unroll
    for (int q = 0; q < 17; ++q) {
        int j = lane + q * 64;
        float e = 0.f;
        if (j < NP1) e = expf(row[j] + vb[j]);
        et[q] = e;
        sm += e;
    }
    #pragma unroll
    for (int o = 32; o; o >>= 1) sm += __shfl_xor(sm, o);
    float A = (i == M_) ? 0.5f : (1.0f / 2048.0f);
    float scale = (A / sm) * 2048.0f;
    #pragma unroll
    for (int q = 0; q < 17; ++q) {
        int j = lane + q * 64;
        if (j < NP1) row[j] = et[q] * scale;
    }
}

__global__ __launch_bounds__(256) void zero_kernel(float* __restrict__ p, int n)
{
    int i = blockIdx.x * 256 + threadIdx.x;
    if (i < n) p[i] = 0.f;
}

extern "C" void kernel_launch(void* const* d_in, const int* in_sizes, int n_in,
                              void* d_out, int out_size, void* d_ws, size_t ws_size,
                              hipStream_t stream)
{
    const float* tf    = (const float*)d_in[0];
    const float* df    = (const float*)d_in[1];
    const float* tl    = (const float*)d_in[2];
    const float* dl    = (const float*)d_in[3];
    const float* alpha = (const float*)d_in[4];
    const float* eps   = (const float*)d_in[5];
    float* out = (float*)d_out;

    const size_t bf_one   = (size_t)B_ * M_ * D_ * 2;           // one bf16 feature matrix
    const size_t sh_bytes = (size_t)B_ * M_ * SSTR * 2;         // fp16 S (interior only)
    const size_t vf       = (size_t)B_ * VSTR;                  // v floats
    const size_t sums_f   = 2 * B_ * 17;                        // sums ping-pong floats
    const size_t invs_f   = (size_t)B_ * M_ * 2;                // inv1+inv2 floats (tier2)
    const size_t need_pre = 2 * bf_one + sh_bytes + (vf + sums_f) * 4 + 512;
    const size_t need_mid = sh_bytes + (vf + sums_f + invs_f) * 4 + 512;

    int initblocks = (int)((vf + sums_f + 255) / 256);

    if (ws_size >= need_pre) {
        unsigned short* tfh = (unsigned short*)d_ws;
        unsigned short* dfh = tfh + (size_t)B_ * M_ * D_;
        _Float16* Sh = (_Float16*)((char*)d_ws + 2 * bf_one);
        float* fbase = (float*)((char*)d_ws + ((2 * bf_one + sh_bytes + 255) & ~(size_t)255));
        float* v      = fbase;
        float* sums_p = v + vf;
        float* ps     = out;

        norms_kernel_t<true><<<(B_ * 2048) / 4, 256, 0, stream>>>(tf, df, nullptr, nullptr, tfh, dfh, v, sums_p);
        gemm_s_kernel<2><<<1024, 256, 0, stream>>>(tfh, dfh, tl, dl, nullptr, nullptr, eps, Sh);

        for (int it = 0; it < NUM_SINK; ++it) {
            rowcol32<<<512, 256, 0, stream>>>(Sh, v, ps, alpha, eps);
            colpass32<<<68, 256, 0, stream>>>(ps, v, sums_p, it);
        }
        final32<<<580, 256, 0, stream>>>(Sh, v, sums_p, alpha, eps, out);
    } else if (ws_size >= need_mid) {
        _Float16* Sh = (_Float16*)d_ws;
        float* fbase = (float*)((char*)d_ws + ((sh_bytes + 255) & ~(size_t)255));
        float* inv1   = fbase;
        float* inv2   = inv1 + B_ * M_;
        float* v      = inv2 + B_ * N_;
        float* sums_p = v + vf;
        float* ps     = out;

        init_hv<<<initblocks, 256, 0, stream>>>(v, sums_p);
        norms_kernel_t<false><<<(B_ * 2048) / 4, 256, 0, stream>>>(tf, df, inv1, inv2, nullptr, nullptr, nullptr, nullptr);
        gemm_s_kernel<1><<<1024, 256, 0, stream>>>(tf, df, tl, dl, inv1, inv2, eps, Sh);

        for (int it = 0; it < NUM_SINK; ++it) {
            rowcol32<<<512, 256, 0, stream>>>(Sh, v, ps, alpha, eps);
            colpass32<<<68, 256, 0, stream>>>(ps, v, sums_p, it);
        }
        final32<<<580, 256, 0, stream>>>(Sh, v, sums_p, alpha, eps, out);
    } else {
        float* S = out;
        float* ws = (float*)d_ws;
        float* inv1 = ws;
        float* inv2 = inv1 + B_ * M_;
        float* u    = inv2 + B_ * N_;
        float* v    = u + B_ * MP1;
        float* pm   = v + B_ * NP1;
        float* ps   = pm + 9 * B_ * NP1;

        zero_kernel<<<(B_ * NP1 + 255) / 256, 256, 0, stream>>>(v, B_ * NP1);
        norms_kernel_t<false><<<(B_ * 2048) / 4, 256, 0, stream>>>(tf, df, inv1, inv2, nullptr, nullptr, nullptr, nullptr);
        gemm_s_kernel<0><<<1024, 256, 0, stream>>>(tf, df, tl, dl, inv1, inv2, eps, S);
        fill_edges_f32<<<(B_ * (NP1 + M_) + 255) / 256, 256, 0, stream>>>(S, alpha, eps);

        int rowblocks = (B_ * MP1 + 3) / 4;
        for (int it = 0; it < NUM_SINK; ++it) {
            row_pass_kernel<<<rowblocks, 256, 0, stream>>>(S, v, u);
            col_pass1_kernel<<<dim3(5, 9, 16), 256, 0, stream>>>(S, u, pm, ps);
            col_pass2_kernel<<<dim3(5, 16), 256, 0, stream>>>(pm, ps, v);
        }
        row_final_kernel<<<rowblocks, 256, 0, stream>>>(S, v);
    }
}

// Round 10
// 150.908 us; speedup vs baseline: 2.3884x; 1.0722x over previous
//
#include <hip/hip_runtime.h>
#include <math.h>

#define B_ 16
#define M_ 1024
#define N_ 1024
#define D_ 512
#define MP1 1025
#define NP1 1025
#define NUM_SINK 8
#define BK 64
#define SSTR 1024        // fp16 S row stride (elements) — interior only, no edges
#define VSTR 1028        // v stride (floats), 16B-aligned
#define NCHK 16          // ps chunks (64 rows each)
// log(1/2048), log(1/2)
#define LOG_NORM (-7.6246189861593985f)
#define LOG_HALF (-0.6931471805599453f)

typedef __attribute__((ext_vector_type(8))) short bf16x8;
typedef __attribute__((ext_vector_type(4))) float f32x4;
typedef __attribute__((ext_vector_type(8))) _Float16 h16x8;

__device__ inline short f2bf(float x) {
    unsigned u = __builtin_bit_cast(unsigned, x);
    u = (u + 0x7FFFu + ((u >> 16) & 1u)) >> 16;
    return (short)u;
}

__device__ inline void gload16(const void* g, void* l) {
    __builtin_amdgcn_global_load_lds(
        (const __attribute__((address_space(1))) unsigned int*)g,
        (__attribute__((address_space(3))) unsigned int*)l, 16, 0, 0);
}

// ---------------- norms (+init of v/sums in block 0): one wave per feature row ----------------
template<bool PRE>
__global__ __launch_bounds__(256) void norms_kernel_t(
    const float* __restrict__ tf, const float* __restrict__ df,
    float* __restrict__ inv1, float* __restrict__ inv2,
    unsigned short* __restrict__ tfh, unsigned short* __restrict__ dfh,
    float* __restrict__ v, float* __restrict__ sums_p)
{
    if (PRE && blockIdx.x == 0) {
        const int nv = B_ * VSTR, ns = 2 * B_ * 17;
        for (int t = threadIdx.x; t < nv + ns; t += 256) {
            if (t < nv) v[t] = 0.f;
            else {
                int u2 = t - nv;
                int p = u2 / (B_ * 17), s = u2 % 17;
                sums_p[u2] = (p == 0 && s == 0) ? 1025.0f : 0.f;
            }
        }
    }
    int w = (blockIdx.x * 256 + threadIdx.x) >> 6;
    int lane = threadIdx.x & 63;
    if (w >= B_ * 2048) return;
    int b = w >> 11;
    int rr = w & 2047;
    const float* src;
    float* dst = nullptr;
    unsigned short* dsth = nullptr;
    if (rr < M_) { src = tf + ((size_t)b * M_ + rr) * D_;
                   if (!PRE) dst = inv1 + b * M_ + rr;
                   if (PRE)  dsth = tfh + ((size_t)b * M_ + rr) * D_; }
    else         { src = df + ((size_t)b * N_ + (rr - M_)) * D_;
                   if (!PRE) dst = inv2 + b * N_ + (rr - M_);
                   if (PRE)  dsth = dfh + ((size_t)b * N_ + (rr - M_)) * D_; }
    float4 x = *(const float4*)(src + lane * 4);
    float4 y = *(const float4*)(src + 256 + lane * 4);
    float ss = x.x*x.x + x.y*x.y + x.z*x.z + x.w*x.w
             + y.x*y.x + y.y*y.y + y.z*y.z + y.w*y.w;
    #pragma unroll
    for (int o = 32; o; o >>= 1) ss += __shfl_xor(ss, o);
    if (PRE) {
        float rn = rsqrtf(ss);
        ushort4 hx, hy;
        hx.x = (unsigned short)f2bf(x.x*rn); hx.y = (unsigned short)f2bf(x.y*rn);
        hx.z = (unsigned short)f2bf(x.z*rn); hx.w = (unsigned short)f2bf(x.w*rn);
        hy.x = (unsigned short)f2bf(y.x*rn); hy.y = (unsigned short)f2bf(y.y*rn);
        hy.z = (unsigned short)f2bf(y.z*rn); hy.w = (unsigned short)f2bf(y.w*rn);
        *(ushort4*)(dsth + lane * 4) = hx;
        *(ushort4*)(dsth + 256 + lane * 4) = hy;
    } else {
        if (lane == 0) *dst = 1.0f / sqrtf(ss);
    }
}

// ---------------- MFMA GEMM + epilogue: S = (cos*mask - 1)/lambda ----------------
// MODE 0: fp32 out (NP1 stride), f2bf staging. MODE 1: fp16 out, f2bf staging.
// MODE 2: fp16 out, global_load_lds from PRESCALED bf16, double-buffered.
template<int MODE>
__global__ __launch_bounds__(256) void gemm_s_kernel(
    const void* __restrict__ A, const void* __restrict__ Bm,
    const float* __restrict__ tl, const float* __restrict__ dl,
    const float* __restrict__ inv1, const float* __restrict__ inv2,
    const float* __restrict__ eps_p, void* __restrict__ Sout)
{
    __shared__ __align__(16) unsigned short As[2][128 * BK];
    __shared__ __align__(16) unsigned short Bs[2][128 * BK];

    int flat = blockIdx.x;
    int swz = (flat & 7) * 128 + (flat >> 3);
    int jb = swz & 7, ib = (swz >> 3) & 7;
    int b  = swz >> 6;
    int i0 = ib * 128;
    int j0 = jb * 128;

    int tid  = threadIdx.x;
    int lane = tid & 63;
    int w    = tid >> 6;
    int wm   = w >> 1, wn = w & 1;

    f32x4 acc[4][4] = {};

    if constexpr (MODE == 2) {
        const unsigned short* Ah = (const unsigned short*)A  + (size_t)b * M_ * D_;
        const unsigned short* Bh = (const unsigned short*)Bm + (size_t)b * N_ * D_;
        int gcol = ((lane & 7) ^ (lane >> 3)) << 3;
        int rloc = lane >> 3;

        auto stage = [&](int k0, int buf) {
            #pragma unroll
            for (int c = 0; c < 4; ++c) {
                int r = (w * 4 + c) * 8 + rloc;
                gload16(Ah + (size_t)(i0 + r) * D_ + k0 + gcol,
                        (char*)As[buf] + (w * 4 + c) * 1024 + lane * 16);
                gload16(Bh + (size_t)(j0 + r) * D_ + k0 + gcol,
                        (char*)Bs[buf] + (w * 4 + c) * 1024 + lane * 16);
            }
        };

        stage(0, 0);
        __syncthreads();
        int cur = 0;
        for (int t = 0; t < D_ / BK; ++t) {
            if (t < D_ / BK - 1) stage((t + 1) * BK, cur ^ 1);
            #pragma unroll
            for (int ks = 0; ks < 2; ++ks) {
                int kb = ks * 64 + ((lane >> 4) << 4);
                bf16x8 af[4], bfr[4];
                #pragma unroll
                for (int m = 0; m < 4; ++m) {
                    int ra = wm * 64 + m * 16 + (lane & 15);
                    af[m] = *(const bf16x8*)((const char*)As[cur] + ra * 128 + (kb ^ ((ra & 7) << 4)));
                    int rb = wn * 64 + m * 16 + (lane & 15);
                    bfr[m] = *(const bf16x8*)((const char*)Bs[cur] + rb * 128 + (kb ^ ((rb & 7) << 4)));
                }
                #pragma unroll
                for (int m = 0; m < 4; ++m)
                    #pragma unroll
                    for (int n = 0; n < 4; ++n)
                        acc[m][n] = __builtin_amdgcn_mfma_f32_16x16x32_bf16(af[m], bfr[n], acc[m][n], 0, 0, 0);
            }
            __syncthreads();
            cur ^= 1;
        }
    } else {
        const float* Ab = (const float*)A  + (size_t)b * M_ * D_;
        const float* Bb = (const float*)Bm + (size_t)b * N_ * D_;
        int seg   = tid & 7;
        int rbase = tid >> 3;
        for (int k0 = 0; k0 < D_; k0 += BK) {
            #pragma unroll
            for (int rr = 0; rr < 4; ++rr) {
                int r = rbase + rr * 32;
                int colx = (seg * 16) ^ ((r & 7) << 4);
                {
                    const float* pa = Ab + (size_t)(i0 + r) * D_ + k0 + seg * 8;
                    float4 a0 = *(const float4*)pa;
                    float4 a1 = *(const float4*)(pa + 4);
                    bf16x8 hv;
                    hv[0] = f2bf(a0.x); hv[1] = f2bf(a0.y); hv[2] = f2bf(a0.z); hv[3] = f2bf(a0.w);
                    hv[4] = f2bf(a1.x); hv[5] = f2bf(a1.y); hv[6] = f2bf(a1.z); hv[7] = f2bf(a1.w);
                    *(bf16x8*)((char*)As[0] + r * 128 + colx) = hv;
                }
                {
                    const float* pb = Bb + (size_t)(j0 + r) * D_ + k0 + seg * 8;
                    float4 b0 = *(const float4*)pb;
                    float4 b1 = *(const float4*)(pb + 4);
                    bf16x8 hv;
                    hv[0] = f2bf(b0.x); hv[1] = f2bf(b0.y); hv[2] = f2bf(b0.z); hv[3] = f2bf(b0.w);
                    hv[4] = f2bf(b1.x); hv[5] = f2bf(b1.y); hv[6] = f2bf(b1.z); hv[7] = f2bf(b1.w);
                    *(bf16x8*)((char*)Bs[0] + r * 128 + colx) = hv;
                }
            }
            __syncthreads();
            #pragma unroll
            for (int ks = 0; ks < 2; ++ks) {
                int kb = ks * 64 + ((lane >> 4) << 4);
                bf16x8 af[4], bfr[4];
                #pragma unroll
                for (int m = 0; m < 4; ++m) {
                    int ra = wm * 64 + m * 16 + (lane & 15);
                    af[m] = *(const bf16x8*)((const char*)As[0] + ra * 128 + (kb ^ ((ra & 7) << 4)));
                    int rb = wn * 64 + m * 16 + (lane & 15);
                    bfr[m] = *(const bf16x8*)((const char*)Bs[0] + rb * 128 + (kb ^ ((rb & 7) << 4)));
                }
                #pragma unroll
                for (int m = 0; m < 4; ++m)
                    #pragma unroll
                    for (int n = 0; n < 4; ++n)
                        acc[m][n] = __builtin_amdgcn_mfma_f32_16x16x32_bf16(af[m], bfr[n], acc[m][n], 0, 0, 0);
            }
            __syncthreads();
        }
    }

    float lam = __expf(eps_p[0]) + 0.03f;
    float inv_lam = 1.0f / lam;
    int crow0 = i0 + wm * 64;
    int ccol0 = j0 + wn * 64;
    int rlane = lane >> 4;
    int clane = lane & 15;

    float invb_[4], dlx_[4], dly_[4];
    #pragma unroll
    for (int n = 0; n < 4; ++n) {
        int j = ccol0 + n * 16 + clane;
        if (MODE != 2) invb_[n] = inv2[b * N_ + j];
        dlx_[n]  = dl[((size_t)b * N_ + j) * 2 + 0];
        dly_[n]  = dl[((size_t)b * N_ + j) * 2 + 1];
    }
    #pragma unroll
    for (int m = 0; m < 4; ++m) {
        #pragma unroll
        for (int reg = 0; reg < 4; ++reg) {
            int i = crow0 + m * 16 + rlane * 4 + reg;
            float inva = (MODE != 2) ? inv1[b * M_ + i] : 1.0f;
            float tlx  = tl[((size_t)b * M_ + i) * 2 + 0];
            float tly  = tl[((size_t)b * M_ + i) * 2 + 1];
            #pragma unroll
            for (int n = 0; n < 4; ++n) {
                float cosv = (MODE == 2) ? acc[m][n][reg]
                                         : acc[m][n][reg] * inva * invb_[n];
                float dx = tlx - dlx_[n];
                float dy = tly - dly_[n];
                float mi = (fmaf(dx, dx, dy * dy) <= 0.09f) ? inv_lam : 0.0f;
                float val = fmaf(cosv, mi, -inv_lam);
                int col = ccol0 + n * 16 + clane;
                if (MODE >= 1) {
                    _Float16* Srow = (_Float16*)Sout + ((size_t)b * M_ + i) * SSTR;
                    Srow[col] = (_Float16)val;
                } else {
                    float* Srow = (float*)Sout + ((size_t)b * MP1 + i) * NP1;
                    Srow[col] = val;
                }
            }
        }
    }
}

// ---------------- init (tier2): zero v + init sums_p ping-pong ----------------
__global__ __launch_bounds__(256) void init_hv(
    float* __restrict__ v, float* __restrict__ sums_p)
{
    int t = blockIdx.x * 256 + threadIdx.x;
    if (t < B_ * VSTR) v[t] = 0.f;
    int u2 = t - B_ * VSTR;
    if (u2 >= 0 && u2 < 2 * B_ * 17) {
        int p = u2 / (B_ * 17), s = u2 % 17;
        sums_p[u2] = (p == 0 && s == 0) ? 1025.0f : 0.f;
    }
}

// ================= fp16 path: fused row-update + column partials =================
// 64 rows/block (4 waves x 16 rows, ALL preloaded -> max MLP). 256 blocks = 1/CU.
__global__ __launch_bounds__(256, 1) void rowcol64(
    const _Float16* __restrict__ Sh, const float* __restrict__ v,
    float* __restrict__ ps,
    const float* __restrict__ alpha_p, const float* __restrict__ eps_p)
{
    int blk = blockIdx.x;           // 0..255
    int b = blk >> 4, k = blk & 15;
    int tid = threadIdx.x, lane = tid & 63, w = tid >> 6;

    __shared__ float red[4][64][17];   // stride-17 words: conflict-free

    const float* vb = v + (size_t)b * VSTR;
    float vreg[16];
    {
        float4 v0 = *(const float4*)(vb + lane * 8);
        float4 v1 = *(const float4*)(vb + lane * 8 + 4);
        float4 v2 = *(const float4*)(vb + 512 + lane * 8);
        float4 v3 = *(const float4*)(vb + 512 + lane * 8 + 4);
        vreg[0]=v0.x; vreg[1]=v0.y; vreg[2]=v0.z; vreg[3]=v0.w;
        vreg[4]=v1.x; vreg[5]=v1.y; vreg[6]=v1.z; vreg[7]=v1.w;
        vreg[8]=v2.x; vreg[9]=v2.y; vreg[10]=v2.z; vreg[11]=v2.w;
        vreg[12]=v3.x; vreg[13]=v3.y; vreg[14]=v3.z; vreg[15]=v3.w;
    }
    float lam = __expf(eps_p[0]) + 0.03f;
    float s_a = (alpha_p[0] - 1.0f) / lam;
    float et16c = __expf(s_a + vb[1024]);

    const _Float16* Sb = Sh + ((size_t)b << 20);
    int rbase = k * 64 + w * 16;

    // preload all 16 rows (32 independent 16B loads in flight)
    h16x8 h0[16], h1[16];
    #pragma unroll
    for (int rr = 0; rr < 16; ++rr) {
        const _Float16* row = Sb + (size_t)(rbase + rr) * SSTR;
        h0[rr] = *(const h16x8*)(row + lane * 8);
        h1[rr] = *(const h16x8*)(row + 512 + lane * 8);
    }

    float creg[16] = {};
    float sum_scale = 0.f;

    #pragma unroll
    for (int rr = 0; rr < 16; ++rr) {
        float et[16];
        float rs = 0.f;
        #pragma unroll
        for (int e = 0; e < 8; ++e) { et[e] = __expf((float)h0[rr][e] + vreg[e]); rs += et[e]; }
        #pragma unroll
        for (int e = 0; e < 8; ++e) { et[8+e] = __expf((float)h1[rr][e] + vreg[8+e]); rs += et[8+e]; }
        #pragma unroll
        for (int o = 32; o; o >>= 1) rs += __shfl_xor(rs, o);
        rs += et16c;                                   // dustbin column term
        float scale = (1.0f / 2048.0f) / rs;           // exp(u_i)
        #pragma unroll
        for (int e = 0; e < 16; ++e) creg[e] += et[e] * scale;
        sum_scale += scale;
    }

    #pragma unroll
    for (int e = 0; e < 16; ++e) red[w][lane][e] = creg[e];
    if (lane == 0) red[w][0][16] = sum_scale;
    __syncthreads();

    float* pso = ps + (size_t)(k * 16 + b) * 1025;
    for (int j = tid; j < 1024; j += 256) {
        int lane_j = (j & 511) >> 3;
        int e_j    = ((j >> 9) << 3) | (j & 7);
        pso[j] = red[0][lane_j][e_j] + red[1][lane_j][e_j]
               + red[2][lane_j][e_j] + red[3][lane_j][e_j];
    }
    if (tid == 0)
        pso[1024] = et16c * (red[0][0][16] + red[1][0][16] + red[2][0][16] + red[3][0][16]);
}

// col update: one wave per (b, 64-col segment). 272 waves = 68 blocks.
__global__ __launch_bounds__(256) void colpass32(
    const float* __restrict__ ps, float* __restrict__ v,
    float* __restrict__ sums_p, int it)
{
    int gw = blockIdx.x * 4 + (threadIdx.x >> 6);
    int lane = threadIdx.x & 63;
    if (gw >= B_ * 17) return;
    int b = gw / 17, seg = gw % 17;
    int j = seg * 64 + lane;
    int par = it & 1;
    float sum_old = 0.f;
    #pragma unroll
    for (int s = 0; s < 17; ++s) sum_old += sums_p[par * (B_ * 17) + b * 17 + s];
    float ev = 0.f;
    if (j <= 1024) {
        size_t vidx = (size_t)b * VSTR + j;
        float vj = v[vidx];
        const float* pp = ps + (size_t)b * 1025 + j;
        float cs = 0.f;
        #pragma unroll
        for (int c = 0; c < NCHK; ++c) cs += pp[(size_t)c * (16 * 1025)];
        cs += 0.5f * __expf(vj) / sum_old;
        float lb = (j == 1024) ? LOG_HALF : LOG_NORM;
        float vn = vj + lb - __logf(cs);
        v[vidx] = vn;
        ev = __expf(vn);
    }
    #pragma unroll
    for (int o = 32; o; o >>= 1) ev += __shfl_xor(ev, o);
    if (lane == 0) sums_p[(par ^ 1) * (B_ * 17) + b * 17 + seg] = ev;
}

// final: blocks <512 write interior rows (+dustbin col); blocks >=512 write dustbin row
__global__ __launch_bounds__(256) void final32(
    const _Float16* __restrict__ Sh, const float* __restrict__ v,
    const float* __restrict__ sums_p,
    const float* __restrict__ alpha_p, const float* __restrict__ eps_p,
    float* __restrict__ out)
{
    int blk = blockIdx.x;
    int tid = threadIdx.x, lane = tid & 63, w = tid >> 6;

    if (blk >= 512) {
        int gw = (blk - 512) * 4 + w;
        if (gw >= B_ * 17) return;
        int b = gw / 17, seg = gw % 17, j = seg * 64 + lane;
        if (j > 1024) return;
        float sumv = 0.f;
        int par = NUM_SINK & 1;
        #pragma unroll
        for (int s = 0; s < 17; ++s) sumv += sums_p[par * (B_ * 17) + b * 17 + s];
        out[((size_t)b * MP1 + 1024) * NP1 + j] = __expf(v[(size_t)b * VSTR + j]) * 1024.0f / sumv;
        return;
    }

    int b = blk >> 5, k = blk & 31;
    const float* vb = v + (size_t)b * VSTR;
    float vreg[16];
    {
        float4 v0 = *(const float4*)(vb + lane * 8);
        float4 v1 = *(const float4*)(vb + lane * 8 + 4);
        float4 v2 = *(const float4*)(vb + 512 + lane * 8);
        float4 v3 = *(const float4*)(vb + 512 + lane * 8 + 4);
        vreg[0]=v0.x; vreg[1]=v0.y; vreg[2]=v0.z; vreg[3]=v0.w;
        vreg[4]=v1.x; vreg[5]=v1.y; vreg[6]=v1.z; vreg[7]=v1.w;
        vreg[8]=v2.x; vreg[9]=v2.y; vreg[10]=v2.z; vreg[11]=v2.w;
        vreg[12]=v3.x; vreg[13]=v3.y; vreg[14]=v3.z; vreg[15]=v3.w;
    }
    float lam = __expf(eps_p[0]) + 0.03f;
    float s_a = (alpha_p[0] - 1.0f) / lam;
    float et16c = __expf(s_a + vb[1024]);

    const _Float16* Sb = Sh + ((size_t)b << 20);
    int rbase = k * 32 + w * 8;

    #pragma unroll
    for (int g = 0; g < 2; ++g) {
        h16x8 h0[4], h1[4];
        #pragma unroll
        for (int rr = 0; rr < 4; ++rr) {
            const _Float16* row = Sb + (size_t)(rbase + g * 4 + rr) * SSTR;
            h0[rr] = *(const h16x8*)(row + lane * 8);
            h1[rr] = *(const h16x8*)(row + 512 + lane * 8);
        }
        #pragma unroll
        for (int rr = 0; rr < 4; ++rr) {
            int r = rbase + g * 4 + rr;
            float et[16];
            float rs = 0.f;
            #pragma unroll
            for (int e = 0; e < 8; ++e) { et[e] = __expf((float)h0[rr][e] + vreg[e]); rs += et[e]; }
            #pragma unroll
            for (int e = 0; e < 8; ++e) { et[8+e] = __expf((float)h1[rr][e] + vreg[8+e]); rs += et[8+e]; }
            #pragma unroll
            for (int o = 32; o; o >>= 1) rs += __shfl_xor(rs, o);
            rs += et16c;
            float sc = 1.0f / rs;   // = exp(u)*2048
            float* orow = out + ((size_t)b * MP1 + r) * NP1;
            float4 o0 = {et[0]*sc,  et[1]*sc,  et[2]*sc,  et[3]*sc};
            float4 o1 = {et[4]*sc,  et[5]*sc,  et[6]*sc,  et[7]*sc};
            float4 o2 = {et[8]*sc,  et[9]*sc,  et[10]*sc, et[11]*sc};
            float4 o3 = {et[12]*sc, et[13]*sc, et[14]*sc, et[15]*sc};
            *(float4*)(orow + lane * 8)           = o0;
            *(float4*)(orow + lane * 8 + 4)       = o1;
            *(float4*)(orow + 512 + lane * 8)     = o2;
            *(float4*)(orow + 512 + lane * 8 + 4) = o3;
            if (lane == 0) orow[1024] = et16c * sc;
        }
    }
}

// ================= fp32 fallback kernels (tier 3, S in d_out) =================

__global__ __launch_bounds__(256) void fill_edges_f32(
    float* __restrict__ Sout, const float* __restrict__ alpha_p, const float* __restrict__ eps_p)
{
    int t = blockIdx.x * 256 + threadIdx.x;
    if (t >= B_ * (NP1 + M_)) return;
    int b = t / (NP1 + M_), r = t % (NP1 + M_);
    float lam = expf(eps_p[0]) + 0.03f;
    float s = (alpha_p[0] - 1.0f) / lam;
    size_t idx;
    if (r < NP1) idx = ((size_t)b * MP1 + M_) * NP1 + r;
    else         idx = ((size_t)b * MP1 + (r - NP1)) * NP1 + N_;
    Sout[idx] = s;
}

__global__ __launch_bounds__(256) void row_pass_kernel(
    const float* __restrict__ S, const float* __restrict__ v, float* __restrict__ u)
{
    int w = (blockIdx.x * 256 + threadIdx.x) >> 6;
    int lane = threadIdx.x & 63;
    if (w >= B_ * MP1) return;
    int b = w / MP1, i = w % MP1;
    const float* row = S + ((size_t)b * MP1 + i) * NP1;
    const float* vb = v + b * NP1;
    float sm = 0.f;
    #pragma unroll
    for (int q = 0; q < 17; ++q) {
        int j = lane + q * 64;
        if (j < NP1) sm += expf(row[j] + vb[j]);
    }
    #pragma unroll
    for (int o = 32; o; o >>= 1) sm += __shfl_xor(sm, o);
    if (lane == 0) {
        float la = (i == M_) ? LOG_HALF : LOG_NORM;
        u[b * MP1 + i] = la - logf(sm);
    }
}

__global__ __launch_bounds__(256) void col_pass1_kernel(
    const float* __restrict__ S, const float* __restrict__ u,
    float* __restrict__ pm, float* __restrict__ ps)
{
    int j = blockIdx.x * 256 + threadIdx.x;
    int b = blockIdx.z;
    int i0 = blockIdx.y * 128;
    int i1 = min(i0 + 128, MP1);
    if (j >= NP1) return;
    const float* p  = S + ((size_t)b * MP1 + i0) * NP1 + j;
    const float* ub = u + b * MP1;
    float sm = 0.f;
    for (int i = i0; i < i1; ++i) {
        sm += expf(*p + ub[i]);
        p += NP1;
    }
    int idx = (blockIdx.y * B_ + b) * NP1 + j;
    pm[idx] = 0.f;
    ps[idx] = sm;
}

__global__ __launch_bounds__(256) void col_pass2_kernel(
    const float* __restrict__ pm, const float* __restrict__ ps, float* __restrict__ v)
{
    int j = blockIdx.x * 256 + threadIdx.x;
    int b = blockIdx.y;
    if (j >= NP1) return;
    float Ssum = 0.f;
    #pragma unroll
    for (int c = 0; c < 9; ++c) Ssum += ps[(c * B_ + b) * NP1 + j];
    float lb = (j == N_) ? LOG_HALF : LOG_NORM;
    v[b * NP1 + j] = lb - logf(Ssum);
}

__global__ __launch_bounds__(256) void row_final_kernel(
    float* __restrict__ S, const float* __restrict__ v)
{
    int w = (blockIdx.x * 256 + threadIdx.x) >> 6;
    int lane = threadIdx.x & 63;
    if (w >= B_ * MP1) return;
    int b = w / MP1, i = w % MP1;
    float* row = S + ((size_t)b * MP1 + i) * NP1;
    const float* vb = v + b * NP1;
    float et[17];
    float sm = 0.f;
    #pragma unroll
    for (int q = 0; q < 17; ++q) {
        int j = lane + q * 64;
        float e = 0.f;
        if (j < NP1) e = expf(row[j] + vb[j]);
        et[q] = e;
        sm += e;
    }
    #pragma unroll
    for (int o = 32; o; o >>= 1) sm += __shfl_xor(sm, o);
    float A = (i == M_) ? 0.5f : (1.0f / 2048.0f);
    float scale = (A / sm) * 2048.0f;
    #pragma unroll
    for (int q = 0; q < 17; ++q) {
        int j = lane + q * 64;
        if (j < NP1) row[j] = et[q] * scale;
    }
}

__global__ __launch_bounds__(256) void zero_kernel(float* __restrict__ p, int n)
{
    int i = blockIdx.x * 256 + threadIdx.x;
    if (i < n) p[i] = 0.f;
}

extern "C" void kernel_launch(void* const* d_in, const int* in_sizes, int n_in,
                              void* d_out, int out_size, void* d_ws, size_t ws_size,
                              hipStream_t stream)
{
    const float* tf    = (const float*)d_in[0];
    const float* df    = (const float*)d_in[1];
    const float* tl    = (const float*)d_in[2];
    const float* dl    = (const float*)d_in[3];
    const float* alpha = (const float*)d_in[4];
    const float* eps   = (const float*)d_in[5];
    float* out = (float*)d_out;

    const size_t bf_one   = (size_t)B_ * M_ * D_ * 2;
    const size_t sh_bytes = (size_t)B_ * M_ * SSTR * 2;
    const size_t vf       = (size_t)B_ * VSTR;
    const size_t sums_f   = 2 * B_ * 17;
    const size_t invs_f   = (size_t)B_ * M_ * 2;
    const size_t need_pre = 2 * bf_one + sh_bytes + (vf + sums_f) * 4 + 512;
    const size_t need_mid = sh_bytes + (vf + sums_f + invs_f) * 4 + 512;

    int initblocks = (int)((vf + sums_f + 255) / 256);

    if (ws_size >= need_pre) {
        unsigned short* tfh = (unsigned short*)d_ws;
        unsigned short* dfh = tfh + (size_t)B_ * M_ * D_;
        _Float16* Sh = (_Float16*)((char*)d_ws + 2 * bf_one);
        float* fbase = (float*)((char*)d_ws + ((2 * bf_one + sh_bytes + 255) & ~(size_t)255));
        float* v      = fbase;
        float* sums_p = v + vf;
        float* ps     = out;

        norms_kernel_t<true><<<(B_ * 2048) / 4, 256, 0, stream>>>(tf, df, nullptr, nullptr, tfh, dfh, v, sums_p);
        gemm_s_kernel<2><<<1024, 256, 0, stream>>>(tfh, dfh, tl, dl, nullptr, nullptr, eps, Sh);

        for (int it = 0; it < NUM_SINK; ++it) {
            rowcol64<<<256, 256, 0, stream>>>(Sh, v, ps, alpha, eps);
            colpass32<<<68, 256, 0, stream>>>(ps, v, sums_p, it);
        }
        final32<<<580, 256, 0, stream>>>(Sh, v, sums_p, alpha, eps, out);
    } else if (ws_size >= need_mid) {
        _Float16* Sh = (_Float16*)d_ws;
        float* fbase = (float*)((char*)d_ws + ((sh_bytes + 255) & ~(size_t)255));
        float* inv1   = fbase;
        float* inv2   = inv1 + B_ * M_;
        float* v      = inv2 + B_ * N_;
        float* sums_p = v + vf;
        float* ps     = out;

        init_hv<<<initblocks, 256, 0, stream>>>(v, sums_p);
        norms_kernel_t<false><<<(B_ * 2048) / 4, 256, 0, stream>>>(tf, df, inv1, inv2, nullptr, nullptr, nullptr, nullptr);
        gemm_s_kernel<1><<<1024, 256, 0, stream>>>(tf, df, tl, dl, inv1, inv2, eps, Sh);

        for (int it = 0; it < NUM_SINK; ++it) {
            rowcol64<<<256, 256, 0, stream>>>(Sh, v, ps, alpha, eps);
            colpass32<<<68, 256, 0, stream>>>(ps, v, sums_p, it);
        }
        final32<<<580, 256, 0, stream>>>(Sh, v, sums_p, alpha, eps, out);
    } else {
        float* S = out;
        float* ws = (float*)d_ws;
        float* inv1 = ws;
        float* inv2 = inv1 + B_ * M_;
        float* u    = inv2 + B_ * N_;
        float* v    = u + B_ * MP1;
        float* pm   = v + B_ * NP1;
        float* ps   = pm + 9 * B_ * NP1;

        zero_kernel<<<(B_ * NP1 + 255) / 256, 256, 0, stream>>>(v, B_ * NP1);
        norms_kernel_t<false><<<(B_ * 2048) / 4, 256, 0, stream>>>(tf, df, inv1, inv2, nullptr, nullptr, nullptr, nullptr);
        gemm_s_kernel<0><<<1024, 256, 0, stream>>>(tf, df, tl, dl, inv1, inv2, eps, S);
        fill_edges_f32<<<(B_ * (NP1 + M_) + 255) / 256, 256, 0, stream>>>(S, alpha, eps);

        int rowblocks = (B_ * MP1 + 3) / 4;
        for (int it = 0; it < NUM_SINK; ++it) {
            row_pass_kernel<<<rowblocks, 256, 0, stream>>>(S, v, u);
            col_pass1_kernel<<<dim3(5, 9, 16), 256, 0, stream>>>(S, u, pm, ps);
            col_pass2_kernel<<<dim3(5, 16), 256, 0, stream>>>(pm, ps, v);
        }
        row_final_kernel<<<rowblocks, 256, 0, stream>>>(S, v);
    }
}